// Round 1
// baseline (410.711 us; speedup 1.0000x reference)
//
#include <hip/hip_runtime.h>
#include <hip/hip_bf16.h>
#include <math.h>

// ---------------- constants for this problem ----------------
#define HDIM 128            // feature/hidden width (F == H == 128)
#define SCAN_B 256

// ---------------- degree count ----------------
__global__ __launch_bounds__(256) void count_kernel(const int* __restrict__ dst,
                                                    int* __restrict__ cnt, int E) {
    int e = blockIdx.x * 256 + threadIdx.x;
    if (e < E) atomicAdd(&cnt[dst[e]], 1);
}

// ---------------- 3-phase exclusive scan over cnt -> rowstart, plus dinv ----------------
__global__ __launch_bounds__(SCAN_B) void scan1_kernel(const int* __restrict__ cnt,
                                                       int* __restrict__ rowstart,
                                                       int* __restrict__ sums, int n) {
    __shared__ int s[SCAN_B];
    int t = threadIdx.x;
    int idx = blockIdx.x * SCAN_B + t;
    int v = (idx < n) ? cnt[idx] : 0;
    s[t] = v;
    __syncthreads();
    for (int off = 1; off < SCAN_B; off <<= 1) {
        int x = (t >= off) ? s[t - off] : 0;
        __syncthreads();
        s[t] += x;
        __syncthreads();
    }
    if (idx < n) rowstart[idx] = s[t];     // block-local inclusive scan (temp)
    if (t == SCAN_B - 1) sums[blockIdx.x] = s[t];
}

__global__ __launch_bounds__(SCAN_B) void scan2_kernel(int* __restrict__ sums, int nb) {
    __shared__ int s[SCAN_B];
    int t = threadIdx.x;
    int v = (t < nb) ? sums[t] : 0;
    s[t] = v;
    __syncthreads();
    for (int off = 1; off < SCAN_B; off <<= 1) {
        int x = (t >= off) ? s[t - off] : 0;
        __syncthreads();
        s[t] += x;
        __syncthreads();
    }
    if (t < nb) sums[t] = s[t] - v;        // exclusive scan of block sums
}

__global__ __launch_bounds__(SCAN_B) void scan3_kernel(const int* __restrict__ cnt,
                                                       int* __restrict__ rowstart,
                                                       const int* __restrict__ sums,
                                                       float* __restrict__ dinv,
                                                       int n, int E) {
    int idx = blockIdx.x * SCAN_B + threadIdx.x;
    if (idx < n) {
        int incl = rowstart[idx];
        rowstart[idx] = incl - cnt[idx] + sums[blockIdx.x];   // global exclusive
        dinv[idx] = rsqrtf((float)(cnt[idx] + 1));            // +1 self-loop
    }
    if (idx == 0) rowstart[n] = E;
}

// ---------------- CSR fill (src + precomputed edge weight) ----------------
__global__ __launch_bounds__(256) void fill_kernel(const int* __restrict__ srcv,
                                                   const int* __restrict__ dstv,
                                                   const int* __restrict__ rowstart,
                                                   int* __restrict__ cursor,
                                                   const float* __restrict__ dinv,
                                                   int* __restrict__ csr_src,
                                                   float* __restrict__ csr_w, int E) {
    int e = blockIdx.x * 256 + threadIdx.x;
    if (e < E) {
        int s = srcv[e], d = dstv[e];
        int slot = atomicAdd(&cursor[d], 1);
        int pos = rowstart[d] + slot;
        csr_src[pos] = s;
        csr_w[pos] = dinv[s] * dinv[d];
    }
}

// ---------------- fp32 GEMM: C[N x 128] = A[N x 128] @ W[128 x 128] ----------------
// block tile 64x128, 256 threads, microtile 4x8
#define BM 64
#define BK 16
__global__ __launch_bounds__(256) void gemm_kernel(const float* __restrict__ A,
                                                   const float* __restrict__ W,
                                                   float* __restrict__ C, int Nrows) {
    __shared__ float As[BM][BK + 1];
    __shared__ float Bs[BK][HDIM];
    int tid = threadIdx.x;
    int row0 = blockIdx.x * BM;
    int ct = tid & 15;   // 16 col-threads * 8 cols
    int rt = tid >> 4;   // 16 row-threads * 4 rows

    float acc[4][8];
#pragma unroll
    for (int i = 0; i < 4; ++i)
#pragma unroll
        for (int j = 0; j < 8; ++j) acc[i][j] = 0.f;

    for (int k0 = 0; k0 < HDIM; k0 += BK) {
        // load A tile: 64 x 16
        {
            int r = tid >> 2, q = tid & 3;
            int grow = row0 + r;
            float4 v = make_float4(0.f, 0.f, 0.f, 0.f);
            if (grow < Nrows) v = *(const float4*)&A[(size_t)grow * HDIM + k0 + q * 4];
            As[r][q * 4 + 0] = v.x;
            As[r][q * 4 + 1] = v.y;
            As[r][q * 4 + 2] = v.z;
            As[r][q * 4 + 3] = v.w;
        }
        // load W tile: 16 x 128
        {
            int kr = tid >> 4;
            int cb = (tid & 15) * 8;
            const float4* wp = (const float4*)&W[(size_t)(k0 + kr) * HDIM + cb];
            float4 v0 = wp[0], v1 = wp[1];
            *(float4*)&Bs[kr][cb] = v0;
            *(float4*)&Bs[kr][cb + 4] = v1;
        }
        __syncthreads();
#pragma unroll
        for (int k = 0; k < BK; ++k) {
            float a[4];
#pragma unroll
            for (int i = 0; i < 4; ++i) a[i] = As[rt * 4 + i][k];
            float4 bv0 = *(float4*)&Bs[k][ct * 8];
            float4 bv1 = *(float4*)&Bs[k][ct * 8 + 4];
            float b[8] = {bv0.x, bv0.y, bv0.z, bv0.w, bv1.x, bv1.y, bv1.z, bv1.w};
#pragma unroll
            for (int i = 0; i < 4; ++i)
#pragma unroll
                for (int j = 0; j < 8; ++j) acc[i][j] = fmaf(a[i], b[j], acc[i][j]);
        }
        __syncthreads();
    }
#pragma unroll
    for (int i = 0; i < 4; ++i) {
        int grow = row0 + rt * 4 + i;
        if (grow < Nrows) {
            float4 o0 = make_float4(acc[i][0], acc[i][1], acc[i][2], acc[i][3]);
            float4 o1 = make_float4(acc[i][4], acc[i][5], acc[i][6], acc[i][7]);
            *(float4*)&C[(size_t)grow * HDIM + ct * 8] = o0;
            *(float4*)&C[(size_t)grow * HDIM + ct * 8 + 4] = o1;
        }
    }
}

// ---------------- aggregation: one wave per node, CSR gather, +bias, ReLU ----------------
__global__ __launch_bounds__(256) void agg_kernel(const float* __restrict__ m,
                                                  const int* __restrict__ rowstart,
                                                  const int* __restrict__ csr_src,
                                                  const float* __restrict__ csr_w,
                                                  const float* __restrict__ dinv,
                                                  const float* __restrict__ bias,
                                                  float* __restrict__ out, int n) {
    int wid = threadIdx.x >> 6;
    int lane = threadIdx.x & 63;
    int node = blockIdx.x * 4 + wid;
    if (node >= n) return;
    const float2* m2 = (const float2*)m;
    float ds = dinv[node];
    float wself = ds * ds;
    float2 v = m2[(size_t)node * 64 + lane];
    float ax = wself * v.x, ay = wself * v.y;
    int p = rowstart[node];
    int pend = rowstart[node + 1];
    for (; p < pend; ++p) {
        int s = csr_src[p];
        float w = csr_w[p];
        float2 u = m2[(size_t)s * 64 + lane];
        ax = fmaf(w, u.x, ax);
        ay = fmaf(w, u.y, ay);
    }
    float2 bv = ((const float2*)bias)[lane];
    ax = fmaxf(ax + bv.x, 0.f);
    ay = fmaxf(ay + bv.y, 0.f);
    ((float2*)out)[(size_t)node * 64 + lane] = make_float2(ax, ay);
}

// ---------------- global max pool (batch sorted; values >= 0 post-ReLU) ----------------
__global__ __launch_bounds__(128) void pool_kernel(const float* __restrict__ h,
                                                   const int* __restrict__ batch,
                                                   unsigned int* __restrict__ g, int n) {
    int t = threadIdx.x;
    int start = blockIdx.x * 128;
    if (start >= n) return;
    int end = min(n, start + 128);
    int cur = batch[start];
    float run = 0.f;
    for (int node = start; node < end; ++node) {
        int gb = batch[node];
        if (gb != cur) {
            atomicMax(&g[cur * HDIM + t], __float_as_uint(run));
            run = 0.f;
            cur = gb;
        }
        run = fmaxf(run, h[(size_t)node * HDIM + t]);
    }
    atomicMax(&g[cur * HDIM + t], __float_as_uint(run));
}

// ---------------- MLP head + log_softmax ----------------
__global__ __launch_bounds__(128) void mlp_kernel(const unsigned int* __restrict__ gbits,
                                                  const float* __restrict__ W3,
                                                  const float* __restrict__ b3,
                                                  const float* __restrict__ W4,
                                                  const float* __restrict__ b4,
                                                  float* __restrict__ out) {
    __shared__ float gs[HDIM];
    __shared__ float r0[HDIM];
    __shared__ float r1[HDIM];
    int j = threadIdx.x;
    int b = blockIdx.x;
    gs[j] = __uint_as_float(gbits[b * HDIM + j]);
    __syncthreads();
    float acc = b3[j];
#pragma unroll 8
    for (int k = 0; k < HDIM; ++k) acc = fmaf(gs[k], W3[k * HDIM + j], acc);
    float z = fmaxf(acc, 0.f);
    r0[j] = z * W4[j * 2 + 0];
    r1[j] = z * W4[j * 2 + 1];
    __syncthreads();
    for (int off = 64; off > 0; off >>= 1) {
        if (j < off) {
            r0[j] += r0[j + off];
            r1[j] += r1[j + off];
        }
        __syncthreads();
    }
    if (j == 0) {
        float l0 = r0[0] + b4[0];
        float l1 = r1[0] + b4[1];
        float mx = fmaxf(l0, l1);
        float lse = mx + logf(expf(l0 - mx) + expf(l1 - mx));
        out[b * 2 + 0] = l0 - lse;
        out[b * 2 + 1] = l1 - lse;
    }
}

extern "C" void kernel_launch(void* const* d_in, const int* in_sizes, int n_in,
                              void* d_out, int out_size, void* d_ws, size_t ws_size,
                              hipStream_t stream) {
    const float* x  = (const float*)d_in[0];
    const float* W1 = (const float*)d_in[1];
    const float* b1 = (const float*)d_in[2];
    const float* W2 = (const float*)d_in[3];
    const float* b2 = (const float*)d_in[4];
    const float* W3 = (const float*)d_in[5];
    const float* b3 = (const float*)d_in[6];
    const float* W4 = (const float*)d_in[7];
    const float* b4 = (const float*)d_in[8];
    const int* ei    = (const int*)d_in[9];
    const int* batch = (const int*)d_in[10];

    const int N = in_sizes[0] / HDIM;   // 50000
    const int E = in_sizes[9] / 2;      // 640000
    const int G = out_size / 2;         // 64
    const int* src = ei;
    const int* dst = ei + E;

    // ---- workspace layout (4-byte units, 64-element aligned blocks) ----
    const int Nr = ((N + 63) / 64) * 64;
    char* wsb = (char*)d_ws;
    size_t o = 0;
    int* cnt = (int*)(wsb + o);            o += (size_t)Nr * 4;
    int* cursor = (int*)(wsb + o);         o += (size_t)Nr * 4;
    unsigned int* g = (unsigned int*)(wsb + o); o += (size_t)G * HDIM * 4;
    size_t zero_bytes = o;                 // cnt + cursor + g zeroed together
    int* sums = (int*)(wsb + o);           o += 256 * 4;
    int* rowstart = (int*)(wsb + o);       o += (size_t)(Nr + 64) * 4;
    float* dinv = (float*)(wsb + o);       o += (size_t)Nr * 4;
    int* csr_src = (int*)(wsb + o);        o += (size_t)E * 4;
    float* csr_w = (float*)(wsb + o);      o += (size_t)E * 4;
    float* m = (float*)(wsb + o);          o += (size_t)N * HDIM * 4;
    float* h = (float*)(wsb + o);          o += (size_t)N * HDIM * 4;
    (void)ws_size; (void)n_in;

    hipMemsetAsync(d_ws, 0, zero_bytes, stream);

    int eblocks = (E + 255) / 256;
    int nb = (N + SCAN_B - 1) / SCAN_B;   // 196 (<=256 required)

    count_kernel<<<eblocks, 256, 0, stream>>>(dst, cnt, E);
    scan1_kernel<<<nb, SCAN_B, 0, stream>>>(cnt, rowstart, sums, N);
    scan2_kernel<<<1, SCAN_B, 0, stream>>>(sums, nb);
    scan3_kernel<<<nb, SCAN_B, 0, stream>>>(cnt, rowstart, sums, dinv, N, E);
    fill_kernel<<<eblocks, 256, 0, stream>>>(src, dst, rowstart, cursor, dinv,
                                             csr_src, csr_w, E);

    int gemm_blocks = (N + BM - 1) / BM;
    int agg_blocks = (N + 3) / 4;

    // layer 1: m = x@W1 ; h = relu(agg(m) + b1)
    gemm_kernel<<<gemm_blocks, 256, 0, stream>>>(x, W1, m, N);
    agg_kernel<<<agg_blocks, 256, 0, stream>>>(m, rowstart, csr_src, csr_w, dinv, b1, h, N);
    // layer 2: m = h@W2 ; h = relu(agg(m) + b2)
    gemm_kernel<<<gemm_blocks, 256, 0, stream>>>(h, W2, m, N);
    agg_kernel<<<agg_blocks, 256, 0, stream>>>(m, rowstart, csr_src, csr_w, dinv, b2, h, N);

    // global max pool
    int pblocks = (N + 127) / 128;
    pool_kernel<<<pblocks, 128, 0, stream>>>(h, batch, g, N);

    // MLP head + log_softmax
    mlp_kernel<<<G, 128, 0, stream>>>(g, W3, b3, W4, b4, (float*)d_out);
}

// Round 2
// 378.345 us; speedup vs baseline: 1.0855x; 1.0855x over previous
//
#include <hip/hip_runtime.h>
#include <hip/hip_bf16.h>
#include <math.h>

// ---------------- constants ----------------
#define HDIM 128
#define SCAN_B 256

typedef short bfrag __attribute__((ext_vector_type(8)));   // 8 bf16 (4 VGPRs)
typedef float f32x4 __attribute__((ext_vector_type(4)));   // 4 fp32 acc

__device__ inline unsigned short f2bf_rne(float x) {
    unsigned u = __float_as_uint(x);
    u = (u + 0x7fffu + ((u >> 16) & 1u)) >> 16;
    return (unsigned short)u;
}

// ---------------- degree count ----------------
__global__ __launch_bounds__(256) void count_kernel(const int* __restrict__ dst,
                                                    int* __restrict__ cnt, int E) {
    int e = blockIdx.x * 256 + threadIdx.x;
    if (e < E) atomicAdd(&cnt[dst[e]], 1);
}

// ---------------- 3-phase exclusive scan -> rowstart, plus dinv ----------------
__global__ __launch_bounds__(SCAN_B) void scan1_kernel(const int* __restrict__ cnt,
                                                       int* __restrict__ rowstart,
                                                       int* __restrict__ sums, int n) {
    __shared__ int s[SCAN_B];
    int t = threadIdx.x;
    int idx = blockIdx.x * SCAN_B + t;
    int v = (idx < n) ? cnt[idx] : 0;
    s[t] = v;
    __syncthreads();
    for (int off = 1; off < SCAN_B; off <<= 1) {
        int x = (t >= off) ? s[t - off] : 0;
        __syncthreads();
        s[t] += x;
        __syncthreads();
    }
    if (idx < n) rowstart[idx] = s[t];
    if (t == SCAN_B - 1) sums[blockIdx.x] = s[t];
}

__global__ __launch_bounds__(SCAN_B) void scan2_kernel(int* __restrict__ sums, int nb) {
    __shared__ int s[SCAN_B];
    int t = threadIdx.x;
    int v = (t < nb) ? sums[t] : 0;
    s[t] = v;
    __syncthreads();
    for (int off = 1; off < SCAN_B; off <<= 1) {
        int x = (t >= off) ? s[t - off] : 0;
        __syncthreads();
        s[t] += x;
        __syncthreads();
    }
    if (t < nb) sums[t] = s[t] - v;
}

__global__ __launch_bounds__(SCAN_B) void scan3_kernel(const int* __restrict__ cnt,
                                                       int* __restrict__ rowstart,
                                                       const int* __restrict__ sums,
                                                       float* __restrict__ dinv,
                                                       int n, int E) {
    int idx = blockIdx.x * SCAN_B + threadIdx.x;
    if (idx < n) {
        int incl = rowstart[idx];
        rowstart[idx] = incl - cnt[idx] + sums[blockIdx.x];
        dinv[idx] = rsqrtf((float)(cnt[idx] + 1));
    }
    if (idx == 0) rowstart[n] = E;
}

// ---------------- CSR fill ----------------
__global__ __launch_bounds__(256) void fill_kernel(const int* __restrict__ srcv,
                                                   const int* __restrict__ dstv,
                                                   const int* __restrict__ rowstart,
                                                   int* __restrict__ cursor,
                                                   const float* __restrict__ dinv,
                                                   int* __restrict__ csr_src,
                                                   float* __restrict__ csr_w, int E) {
    int e = blockIdx.x * 256 + threadIdx.x;
    if (e < E) {
        int s = srcv[e], d = dstv[e];
        int slot = atomicAdd(&cursor[d], 1);
        int pos = rowstart[d] + slot;
        csr_src[pos] = s;
        csr_w[pos] = dinv[s] * dinv[d];
    }
}

// ---------------- W -> fragment-ordered bf16 hi/lo ----------------
// gemm reads: element W[k][n] at frag offset ((kt*8+nt)*64 + lane)*8 + j
// with k = kt*32 + (lane>>4)*8 + j, n = nt*16 + (lane&15)
__global__ __launch_bounds__(256) void wfrag_kernel(const float* __restrict__ W,
                                                    unsigned short* __restrict__ whi,
                                                    unsigned short* __restrict__ wlo) {
    int idx = blockIdx.x * 256 + threadIdx.x;     // 0..16383
    int k = idx >> 7;
    int n = idx & 127;
    int kt = k >> 5, q = (k & 31) >> 3, j = k & 7;
    int nt = n >> 4, lane = q * 16 + (n & 15);
    int o = ((kt * 8 + nt) * 64 + lane) * 8 + j;
    float x = W[idx];
    unsigned short hb = f2bf_rne(x);
    float hf = __uint_as_float(((unsigned)hb) << 16);
    unsigned short lb = f2bf_rne(x - hf);
    whi[o] = hb;
    wlo[o] = lb;
}

// ---------------- MFMA GEMM: C_bf16[N x 128] = A_f32[N x 128] @ W[128 x 128] ----------------
// split precision: C ~= Ah*Wh + Al*Wh + Ah*Wl  (fp32 accumulate)
#define GBM 128
#define APAD 132   // 33 b128-units per row (odd) -> 2-way LDS aliasing only (free)
__global__ __launch_bounds__(256, 2) void gemm_mfma_kernel(
        const float* __restrict__ A,
        const unsigned short* __restrict__ whi,
        const unsigned short* __restrict__ wlo,
        unsigned short* __restrict__ C, int Nrows) {
    __shared__ float As[GBM * APAD];
    int tid = threadIdx.x;
    int row0 = blockIdx.x * GBM;

    // stage A tile (128 rows x 128 k, fp32), coalesced float4
    {
        int f = tid & 31;       // float4 column
        int rbase = tid >> 5;   // 0..7
#pragma unroll
        for (int i = 0; i < 16; ++i) {
            int r = rbase + i * 8;
            int gr = row0 + r;
            float4 v = make_float4(0.f, 0.f, 0.f, 0.f);
            if (gr < Nrows) v = *(const float4*)&A[(size_t)gr * HDIM + f * 4];
            *(float4*)&As[r * APAD + f * 4] = v;
        }
    }
    __syncthreads();

    int w = tid >> 6, L = tid & 63;
    int lm = L & 15, lq = L >> 4;

    f32x4 acc[2][8];
#pragma unroll
    for (int mt = 0; mt < 2; ++mt)
#pragma unroll
        for (int nt = 0; nt < 8; ++nt) acc[mt][nt] = (f32x4)(0.f);

#pragma unroll
    for (int kt = 0; kt < 4; ++kt) {
        bfrag ah[2], al[2];
#pragma unroll
        for (int mt = 0; mt < 2; ++mt) {
            int row = w * 32 + mt * 16 + lm;
            const float* p = &As[row * APAD + kt * 32 + lq * 8];
            float4 v0 = *(const float4*)p;
            float4 v1 = *(const float4*)(p + 4);
            float xv[8] = {v0.x, v0.y, v0.z, v0.w, v1.x, v1.y, v1.z, v1.w};
            bfrag hh, ll;
#pragma unroll
            for (int j = 0; j < 8; ++j) {
                float x = xv[j];
                unsigned short hb = f2bf_rne(x);
                float hf = __uint_as_float(((unsigned)hb) << 16);
                unsigned short lb = f2bf_rne(x - hf);
                hh[j] = (short)hb;
                ll[j] = (short)lb;
            }
            ah[mt] = hh;
            al[mt] = ll;
        }
#pragma unroll
        for (int nt = 0; nt < 8; ++nt) {
            int o = ((kt * 8 + nt) * 64 + L) * 8;
            bfrag wh = *(const bfrag*)&whi[o];
            bfrag wl = *(const bfrag*)&wlo[o];
#pragma unroll
            for (int mt = 0; mt < 2; ++mt) {
                acc[mt][nt] = __builtin_amdgcn_mfma_f32_16x16x32_bf16(ah[mt], wh, acc[mt][nt], 0, 0, 0);
                acc[mt][nt] = __builtin_amdgcn_mfma_f32_16x16x32_bf16(al[mt], wh, acc[mt][nt], 0, 0, 0);
                acc[mt][nt] = __builtin_amdgcn_mfma_f32_16x16x32_bf16(ah[mt], wl, acc[mt][nt], 0, 0, 0);
            }
        }
    }

    // epilogue: C/D layout col=lane&15, row=(lane>>4)*4+reg ; write bf16
#pragma unroll
    for (int mt = 0; mt < 2; ++mt)
#pragma unroll
        for (int i = 0; i < 4; ++i) {
            int gr = row0 + w * 32 + mt * 16 + lq * 4 + i;
            if (gr < Nrows) {
#pragma unroll
                for (int nt = 0; nt < 8; ++nt)
                    C[(size_t)gr * HDIM + nt * 16 + lm] = f2bf_rne(acc[mt][nt][i]);
            }
        }
}

// ---------------- aggregation: one wave per node, bf16 gather, fp32 accumulate ----------------
__global__ __launch_bounds__(256) void agg_kernel(const unsigned int* __restrict__ m2,
                                                  const int* __restrict__ rowstart,
                                                  const int* __restrict__ csr_src,
                                                  const float* __restrict__ csr_w,
                                                  const float* __restrict__ dinv,
                                                  const float* __restrict__ bias,
                                                  float* __restrict__ out, int n) {
    int wid = threadIdx.x >> 6;
    int lane = threadIdx.x & 63;
    int node = blockIdx.x * 4 + wid;
    if (node >= n) return;
    float ds = dinv[node];
    float wself = ds * ds;
    unsigned v = m2[(size_t)node * 64 + lane];
    float ax = __uint_as_float(v << 16) * wself;
    float ay = __uint_as_float(v & 0xffff0000u) * wself;
    int p = rowstart[node];
    int pend = rowstart[node + 1];
    for (; p < pend; ++p) {
        int s = csr_src[p];
        float wgt = csr_w[p];
        unsigned u = m2[(size_t)s * 64 + lane];
        ax = fmaf(wgt, __uint_as_float(u << 16), ax);
        ay = fmaf(wgt, __uint_as_float(u & 0xffff0000u), ay);
    }
    float2 bv = ((const float2*)bias)[lane];
    ax = fmaxf(ax + bv.x, 0.f);
    ay = fmaxf(ay + bv.y, 0.f);
    ((float2*)out)[(size_t)node * 64 + lane] = make_float2(ax, ay);
}

// ---------------- global max pool (batch sorted; values >= 0 post-ReLU) ----------------
__global__ __launch_bounds__(128) void pool_kernel(const float* __restrict__ h,
                                                   const int* __restrict__ batch,
                                                   unsigned int* __restrict__ g, int n) {
    int t = threadIdx.x;
    int start = blockIdx.x * 128;
    if (start >= n) return;
    int end = min(n, start + 128);
    int cur = batch[start];
    float run = 0.f;
    for (int node = start; node < end; ++node) {
        int gb = batch[node];
        if (gb != cur) {
            atomicMax(&g[cur * HDIM + t], __float_as_uint(run));
            run = 0.f;
            cur = gb;
        }
        run = fmaxf(run, h[(size_t)node * HDIM + t]);
    }
    atomicMax(&g[cur * HDIM + t], __float_as_uint(run));
}

// ---------------- MLP head + log_softmax ----------------
__global__ __launch_bounds__(128) void mlp_kernel(const unsigned int* __restrict__ gbits,
                                                  const float* __restrict__ W3,
                                                  const float* __restrict__ b3,
                                                  const float* __restrict__ W4,
                                                  const float* __restrict__ b4,
                                                  float* __restrict__ out) {
    __shared__ float gs[HDIM];
    __shared__ float r0[HDIM];
    __shared__ float r1[HDIM];
    int j = threadIdx.x;
    int b = blockIdx.x;
    gs[j] = __uint_as_float(gbits[b * HDIM + j]);
    __syncthreads();
    float acc = b3[j];
#pragma unroll 8
    for (int k = 0; k < HDIM; ++k) acc = fmaf(gs[k], W3[k * HDIM + j], acc);
    float z = fmaxf(acc, 0.f);
    r0[j] = z * W4[j * 2 + 0];
    r1[j] = z * W4[j * 2 + 1];
    __syncthreads();
    for (int off = 64; off > 0; off >>= 1) {
        if (j < off) {
            r0[j] += r0[j + off];
            r1[j] += r1[j + off];
        }
        __syncthreads();
    }
    if (j == 0) {
        float l0 = r0[0] + b4[0];
        float l1 = r1[0] + b4[1];
        float mx = fmaxf(l0, l1);
        float lse = mx + logf(expf(l0 - mx) + expf(l1 - mx));
        out[b * 2 + 0] = l0 - lse;
        out[b * 2 + 1] = l1 - lse;
    }
}

extern "C" void kernel_launch(void* const* d_in, const int* in_sizes, int n_in,
                              void* d_out, int out_size, void* d_ws, size_t ws_size,
                              hipStream_t stream) {
    const float* x  = (const float*)d_in[0];
    const float* W1 = (const float*)d_in[1];
    const float* b1 = (const float*)d_in[2];
    const float* W2 = (const float*)d_in[3];
    const float* b2 = (const float*)d_in[4];
    const float* W3 = (const float*)d_in[5];
    const float* b3 = (const float*)d_in[6];
    const float* W4 = (const float*)d_in[7];
    const float* b4 = (const float*)d_in[8];
    const int* ei    = (const int*)d_in[9];
    const int* batch = (const int*)d_in[10];

    const int N = in_sizes[0] / HDIM;   // 50000
    const int E = in_sizes[9] / 2;      // 640000
    const int G = out_size / 2;         // 64
    const int* src = ei;
    const int* dst = ei + E;

    // ---- workspace layout ----
    const int Nr = ((N + 63) / 64) * 64;
    char* wsb = (char*)d_ws;
    size_t o = 0;
    int* cnt = (int*)(wsb + o);            o += (size_t)Nr * 4;
    int* cursor = (int*)(wsb + o);         o += (size_t)Nr * 4;
    unsigned int* g = (unsigned int*)(wsb + o); o += (size_t)G * HDIM * 4;
    size_t zero_bytes = o;                 // cnt + cursor + g zeroed together
    int* sums = (int*)(wsb + o);           o += 256 * 4;
    int* rowstart = (int*)(wsb + o);       o += (size_t)(Nr + 64) * 4;
    float* dinv = (float*)(wsb + o);       o += (size_t)Nr * 4;
    int* csr_src = (int*)(wsb + o);        o += (size_t)E * 4;
    float* csr_w = (float*)(wsb + o);      o += (size_t)E * 4;
    unsigned short* wf1h = (unsigned short*)(wsb + o); o += (size_t)HDIM * HDIM * 2;
    unsigned short* wf1l = (unsigned short*)(wsb + o); o += (size_t)HDIM * HDIM * 2;
    unsigned short* wf2h = (unsigned short*)(wsb + o); o += (size_t)HDIM * HDIM * 2;
    unsigned short* wf2l = (unsigned short*)(wsb + o); o += (size_t)HDIM * HDIM * 2;
    unsigned short* m = (unsigned short*)(wsb + o);    o += (size_t)Nr * HDIM * 2;
    float* h = (float*)(wsb + o);          o += (size_t)Nr * HDIM * 4;
    (void)ws_size; (void)n_in;

    hipMemsetAsync(d_ws, 0, zero_bytes, stream);

    int eblocks = (E + 255) / 256;
    int nb = (N + SCAN_B - 1) / SCAN_B;

    count_kernel<<<eblocks, 256, 0, stream>>>(dst, cnt, E);
    scan1_kernel<<<nb, SCAN_B, 0, stream>>>(cnt, rowstart, sums, N);
    scan2_kernel<<<1, SCAN_B, 0, stream>>>(sums, nb);
    scan3_kernel<<<nb, SCAN_B, 0, stream>>>(cnt, rowstart, sums, dinv, N, E);
    fill_kernel<<<eblocks, 256, 0, stream>>>(src, dst, rowstart, cursor, dinv,
                                             csr_src, csr_w, E);

    wfrag_kernel<<<64, 256, 0, stream>>>(W1, wf1h, wf1l);
    wfrag_kernel<<<64, 256, 0, stream>>>(W2, wf2h, wf2l);

    int gemm_blocks = (N + GBM - 1) / GBM;
    int agg_blocks = (N + 3) / 4;

    // layer 1
    gemm_mfma_kernel<<<gemm_blocks, 256, 0, stream>>>(x, wf1h, wf1l, m, N);
    agg_kernel<<<agg_blocks, 256, 0, stream>>>((const unsigned int*)m, rowstart, csr_src,
                                               csr_w, dinv, b1, h, N);
    // layer 2
    gemm_mfma_kernel<<<gemm_blocks, 256, 0, stream>>>(h, wf2h, wf2l, m, N);
    agg_kernel<<<agg_blocks, 256, 0, stream>>>((const unsigned int*)m, rowstart, csr_src,
                                               csr_w, dinv, b2, h, N);

    // global max pool
    int pblocks = (N + 127) / 128;
    pool_kernel<<<pblocks, 128, 0, stream>>>(h, batch, g, N);

    // MLP head + log_softmax
    mlp_kernel<<<G, 128, 0, stream>>>(g, W3, b3, W4, b4, (float*)d_out);
}

// Round 3
// 286.870 us; speedup vs baseline: 1.4317x; 1.3189x over previous
//
#include <hip/hip_runtime.h>
#include <hip/hip_bf16.h>
#include <math.h>

// ---------------- constants ----------------
#define HDIM 128
#define SCAN_B 256

typedef short bfrag __attribute__((ext_vector_type(8)));   // 8 bf16 (4 VGPRs)
typedef float f32x4 __attribute__((ext_vector_type(4)));   // 4 fp32 acc

__device__ inline unsigned short f2bf_rne(float x) {
    unsigned u = __float_as_uint(x);
    u = (u + 0x7fffu + ((u >> 16) & 1u)) >> 16;
    return (unsigned short)u;
}
__device__ inline float bf_lo(unsigned u) { return __uint_as_float(u << 16); }
__device__ inline float bf_hi(unsigned u) { return __uint_as_float(u & 0xffff0000u); }

// ---------------- degree count ----------------
__global__ __launch_bounds__(256) void count_kernel(const int* __restrict__ dst,
                                                    int* __restrict__ cnt, int E) {
    int e = blockIdx.x * 256 + threadIdx.x;
    if (e < E) atomicAdd(&cnt[dst[e]], 1);
}

// ---------------- 3-phase exclusive scan -> rowstart, plus dinv ----------------
__global__ __launch_bounds__(SCAN_B) void scan1_kernel(const int* __restrict__ cnt,
                                                       int* __restrict__ rowstart,
                                                       int* __restrict__ sums, int n) {
    __shared__ int s[SCAN_B];
    int t = threadIdx.x;
    int idx = blockIdx.x * SCAN_B + t;
    int v = (idx < n) ? cnt[idx] : 0;
    s[t] = v;
    __syncthreads();
    for (int off = 1; off < SCAN_B; off <<= 1) {
        int x = (t >= off) ? s[t - off] : 0;
        __syncthreads();
        s[t] += x;
        __syncthreads();
    }
    if (idx < n) rowstart[idx] = s[t];
    if (t == SCAN_B - 1) sums[blockIdx.x] = s[t];
}

__global__ __launch_bounds__(SCAN_B) void scan2_kernel(int* __restrict__ sums, int nb) {
    __shared__ int s[SCAN_B];
    int t = threadIdx.x;
    int v = (t < nb) ? sums[t] : 0;
    s[t] = v;
    __syncthreads();
    for (int off = 1; off < SCAN_B; off <<= 1) {
        int x = (t >= off) ? s[t - off] : 0;
        __syncthreads();
        s[t] += x;
        __syncthreads();
    }
    if (t < nb) sums[t] = s[t] - v;
}

__global__ __launch_bounds__(SCAN_B) void scan3_kernel(const int* __restrict__ cnt,
                                                       int* __restrict__ rowstart,
                                                       const int* __restrict__ sums,
                                                       float* __restrict__ dinv,
                                                       int n, int E) {
    int idx = blockIdx.x * SCAN_B + threadIdx.x;
    if (idx < n) {
        int incl = rowstart[idx];
        rowstart[idx] = incl - cnt[idx] + sums[blockIdx.x];
        dinv[idx] = rsqrtf((float)(cnt[idx] + 1));
    }
    if (idx == 0) rowstart[n] = E;
}

// ---------------- CSR fill: fused (src, weight) pairs ----------------
__global__ __launch_bounds__(256) void fill_kernel(const int* __restrict__ srcv,
                                                   const int* __restrict__ dstv,
                                                   const int* __restrict__ rowstart,
                                                   int* __restrict__ cursor,
                                                   const float* __restrict__ dinv,
                                                   int2* __restrict__ csr, int E) {
    int e = blockIdx.x * 256 + threadIdx.x;
    if (e < E) {
        int s = srcv[e], d = dstv[e];
        int slot = atomicAdd(&cursor[d], 1);
        int pos = rowstart[d] + slot;
        csr[pos] = make_int2(s, __float_as_int(dinv[s] * dinv[d]));
    }
}

// ---------------- W -> fragment-ordered bf16 hi/lo ----------------
// gemm reads: element W[k][n] at frag offset ((kt*8+nt)*64 + lane)*8 + j
// with k = kt*32 + (lane>>4)*8 + j, n = nt*16 + (lane&15)
__global__ __launch_bounds__(256) void wfrag_kernel(const float* __restrict__ W,
                                                    unsigned short* __restrict__ whi,
                                                    unsigned short* __restrict__ wlo) {
    int idx = blockIdx.x * 256 + threadIdx.x;     // 0..16383
    int k = idx >> 7;
    int n = idx & 127;
    int kt = k >> 5, q = (k & 31) >> 3, j = k & 7;
    int nt = n >> 4, lane = q * 16 + (n & 15);
    int o = ((kt * 8 + nt) * 64 + lane) * 8 + j;
    float x = W[idx];
    unsigned short hb = f2bf_rne(x);
    float hf = __uint_as_float(((unsigned)hb) << 16);
    unsigned short lb = f2bf_rne(x - hf);
    whi[o] = hb;
    wlo[o] = lb;
}

// ---------------- MFMA GEMM, LDS-free: C_bf16[N x 128] = A_f32[N x 128] @ W ----------------
// A rows have zero reuse across the kernel (all 128 cols in one block) -> direct
// fragment loads from global; per kt each 16-row group touches exactly one 128B line/row.
// split precision: C ~= Ah*Wh + Al*Wh + Ah*Wl  (fp32 accumulate)
#define GBM 128
__global__ __launch_bounds__(256) void gemm_mfma_kernel(
        const float* __restrict__ A,
        const unsigned short* __restrict__ whi,
        const unsigned short* __restrict__ wlo,
        unsigned short* __restrict__ C, int Nrows) {
    int tid = threadIdx.x;
    int w = tid >> 6, L = tid & 63;
    int lm = L & 15, lq = L >> 4;
    int row0 = blockIdx.x * GBM + w * 32;

    f32x4 acc[2][8];
#pragma unroll
    for (int mt = 0; mt < 2; ++mt)
#pragma unroll
        for (int nt = 0; nt < 8; ++nt) acc[mt][nt] = (f32x4)(0.f);

#pragma unroll
    for (int kt = 0; kt < 4; ++kt) {
        bfrag ah[2], al[2];
#pragma unroll
        for (int mt = 0; mt < 2; ++mt) {
            int gr = row0 + mt * 16 + lm;
            float4 v0 = make_float4(0.f, 0.f, 0.f, 0.f);
            float4 v1 = v0;
            if (gr < Nrows) {
                const float* p = &A[(size_t)gr * HDIM + kt * 32 + lq * 8];
                v0 = *(const float4*)p;
                v1 = *(const float4*)(p + 4);
            }
            float xv[8] = {v0.x, v0.y, v0.z, v0.w, v1.x, v1.y, v1.z, v1.w};
            bfrag hh, ll;
#pragma unroll
            for (int j = 0; j < 8; ++j) {
                float x = xv[j];
                unsigned short hb = f2bf_rne(x);
                float hf = __uint_as_float(((unsigned)hb) << 16);
                unsigned short lb = f2bf_rne(x - hf);
                hh[j] = (short)hb;
                ll[j] = (short)lb;
            }
            ah[mt] = hh;
            al[mt] = ll;
        }
#pragma unroll
        for (int nt = 0; nt < 8; ++nt) {
            int o = ((kt * 8 + nt) * 64 + L) * 8;
            bfrag wh = *(const bfrag*)&whi[o];
            bfrag wl = *(const bfrag*)&wlo[o];
#pragma unroll
            for (int mt = 0; mt < 2; ++mt) {
                acc[mt][nt] = __builtin_amdgcn_mfma_f32_16x16x32_bf16(ah[mt], wh, acc[mt][nt], 0, 0, 0);
                acc[mt][nt] = __builtin_amdgcn_mfma_f32_16x16x32_bf16(al[mt], wh, acc[mt][nt], 0, 0, 0);
                acc[mt][nt] = __builtin_amdgcn_mfma_f32_16x16x32_bf16(ah[mt], wl, acc[mt][nt], 0, 0, 0);
            }
        }
    }

    // epilogue: C/D layout col=lane&15, row=(lane>>4)*4+reg ; write bf16
#pragma unroll
    for (int mt = 0; mt < 2; ++mt)
#pragma unroll
        for (int i = 0; i < 4; ++i) {
            int gr = row0 + mt * 16 + lq * 4 + i;
            if (gr < Nrows) {
#pragma unroll
                for (int nt = 0; nt < 8; ++nt)
                    C[(size_t)gr * HDIM + nt * 16 + lm] = f2bf_rne(acc[mt][nt][i]);
            }
        }
}

// ---------------- aggregation: wave/node, unroll-4 gather, fp32 accumulate ----------------
__global__ __launch_bounds__(256) void agg_kernel(const unsigned int* __restrict__ m2,
                                                  const int* __restrict__ rowstart,
                                                  const int2* __restrict__ csr,
                                                  const float* __restrict__ dinv,
                                                  const float* __restrict__ bias,
                                                  float* __restrict__ out, int n) {
    int wid = threadIdx.x >> 6;
    int lane = threadIdx.x & 63;
    int node = blockIdx.x * 4 + wid;
    if (node >= n) return;
    float ds = dinv[node];
    float wself = ds * ds;
    unsigned v = m2[(size_t)node * 64 + lane];
    float ax = bf_lo(v) * wself;
    float ay = bf_hi(v) * wself;
    int p = rowstart[node];
    int pend = rowstart[node + 1];
    for (; p + 4 <= pend; p += 4) {
        int2 e0 = csr[p], e1 = csr[p + 1], e2 = csr[p + 2], e3 = csr[p + 3];
        unsigned u0 = m2[(size_t)e0.x * 64 + lane];
        unsigned u1 = m2[(size_t)e1.x * 64 + lane];
        unsigned u2 = m2[(size_t)e2.x * 64 + lane];
        unsigned u3 = m2[(size_t)e3.x * 64 + lane];
        float w0 = __int_as_float(e0.y), w1 = __int_as_float(e1.y);
        float w2 = __int_as_float(e2.y), w3 = __int_as_float(e3.y);
        ax = fmaf(w0, bf_lo(u0), ax); ay = fmaf(w0, bf_hi(u0), ay);
        ax = fmaf(w1, bf_lo(u1), ax); ay = fmaf(w1, bf_hi(u1), ay);
        ax = fmaf(w2, bf_lo(u2), ax); ay = fmaf(w2, bf_hi(u2), ay);
        ax = fmaf(w3, bf_lo(u3), ax); ay = fmaf(w3, bf_hi(u3), ay);
    }
    for (; p < pend; ++p) {
        int2 e = csr[p];
        unsigned u = m2[(size_t)e.x * 64 + lane];
        float wgt = __int_as_float(e.y);
        ax = fmaf(wgt, bf_lo(u), ax);
        ay = fmaf(wgt, bf_hi(u), ay);
    }
    float2 bv = ((const float2*)bias)[lane];
    ax = fmaxf(ax + bv.x, 0.f);
    ay = fmaxf(ay + bv.y, 0.f);
    ((float2*)out)[(size_t)node * 64 + lane] = make_float2(ax, ay);
}

// ---------------- global max pool (batch sorted; values >= 0 post-ReLU) ----------------
#define POOL_NODES 32
__global__ __launch_bounds__(128) void pool_kernel(const float* __restrict__ h,
                                                   const int* __restrict__ batch,
                                                   unsigned int* __restrict__ g, int n) {
    int t = threadIdx.x;
    int start = blockIdx.x * POOL_NODES;
    if (start >= n) return;
    int end = min(n, start + POOL_NODES);
    int cur = batch[start];
    float run = 0.f;
    for (int node = start; node < end; ++node) {
        int gb = batch[node];
        if (gb != cur) {
            atomicMax(&g[cur * HDIM + t], __float_as_uint(run));
            run = 0.f;
            cur = gb;
        }
        run = fmaxf(run, h[(size_t)node * HDIM + t]);
    }
    atomicMax(&g[cur * HDIM + t], __float_as_uint(run));
}

// ---------------- MLP head + log_softmax ----------------
__global__ __launch_bounds__(128) void mlp_kernel(const unsigned int* __restrict__ gbits,
                                                  const float* __restrict__ W3,
                                                  const float* __restrict__ b3,
                                                  const float* __restrict__ W4,
                                                  const float* __restrict__ b4,
                                                  float* __restrict__ out) {
    __shared__ float gs[HDIM];
    __shared__ float r0[HDIM];
    __shared__ float r1[HDIM];
    int j = threadIdx.x;
    int b = blockIdx.x;
    gs[j] = __uint_as_float(gbits[b * HDIM + j]);
    __syncthreads();
    float acc = b3[j];
#pragma unroll 8
    for (int k = 0; k < HDIM; ++k) acc = fmaf(gs[k], W3[k * HDIM + j], acc);
    float z = fmaxf(acc, 0.f);
    r0[j] = z * W4[j * 2 + 0];
    r1[j] = z * W4[j * 2 + 1];
    __syncthreads();
    for (int off = 64; off > 0; off >>= 1) {
        if (j < off) {
            r0[j] += r0[j + off];
            r1[j] += r1[j + off];
        }
        __syncthreads();
    }
    if (j == 0) {
        float l0 = r0[0] + b4[0];
        float l1 = r1[0] + b4[1];
        float mx = fmaxf(l0, l1);
        float lse = mx + logf(expf(l0 - mx) + expf(l1 - mx));
        out[b * 2 + 0] = l0 - lse;
        out[b * 2 + 1] = l1 - lse;
    }
}

extern "C" void kernel_launch(void* const* d_in, const int* in_sizes, int n_in,
                              void* d_out, int out_size, void* d_ws, size_t ws_size,
                              hipStream_t stream) {
    const float* x  = (const float*)d_in[0];
    const float* W1 = (const float*)d_in[1];
    const float* b1 = (const float*)d_in[2];
    const float* W2 = (const float*)d_in[3];
    const float* b2 = (const float*)d_in[4];
    const float* W3 = (const float*)d_in[5];
    const float* b3 = (const float*)d_in[6];
    const float* W4 = (const float*)d_in[7];
    const float* b4 = (const float*)d_in[8];
    const int* ei    = (const int*)d_in[9];
    const int* batch = (const int*)d_in[10];

    const int N = in_sizes[0] / HDIM;   // 50000
    const int E = in_sizes[9] / 2;      // 640000
    const int G = out_size / 2;         // 64
    const int* src = ei;
    const int* dst = ei + E;

    // ---- workspace layout ----
    const int Nr = ((N + 63) / 64) * 64;
    char* wsb = (char*)d_ws;
    size_t o = 0;
    int* cnt = (int*)(wsb + o);            o += (size_t)Nr * 4;
    int* cursor = (int*)(wsb + o);         o += (size_t)Nr * 4;
    unsigned int* g = (unsigned int*)(wsb + o); o += (size_t)G * HDIM * 4;
    size_t zero_bytes = o;                 // cnt + cursor + g zeroed together
    int* sums = (int*)(wsb + o);           o += 256 * 4;
    int* rowstart = (int*)(wsb + o);       o += (size_t)(Nr + 64) * 4;
    float* dinv = (float*)(wsb + o);       o += (size_t)Nr * 4;
    int2* csr = (int2*)(wsb + o);          o += (size_t)E * 8;
    unsigned short* wf1h = (unsigned short*)(wsb + o); o += (size_t)HDIM * HDIM * 2;
    unsigned short* wf1l = (unsigned short*)(wsb + o); o += (size_t)HDIM * HDIM * 2;
    unsigned short* wf2h = (unsigned short*)(wsb + o); o += (size_t)HDIM * HDIM * 2;
    unsigned short* wf2l = (unsigned short*)(wsb + o); o += (size_t)HDIM * HDIM * 2;
    unsigned short* m = (unsigned short*)(wsb + o);    o += (size_t)Nr * HDIM * 2;
    float* h = (float*)(wsb + o);          o += (size_t)Nr * HDIM * 4;
    (void)ws_size; (void)n_in;

    hipMemsetAsync(d_ws, 0, zero_bytes, stream);

    int eblocks = (E + 255) / 256;
    int nb = (N + SCAN_B - 1) / SCAN_B;

    count_kernel<<<eblocks, 256, 0, stream>>>(dst, cnt, E);
    scan1_kernel<<<nb, SCAN_B, 0, stream>>>(cnt, rowstart, sums, N);
    scan2_kernel<<<1, SCAN_B, 0, stream>>>(sums, nb);
    scan3_kernel<<<nb, SCAN_B, 0, stream>>>(cnt, rowstart, sums, dinv, N, E);
    fill_kernel<<<eblocks, 256, 0, stream>>>(src, dst, rowstart, cursor, dinv, csr, E);

    wfrag_kernel<<<64, 256, 0, stream>>>(W1, wf1h, wf1l);
    wfrag_kernel<<<64, 256, 0, stream>>>(W2, wf2h, wf2l);

    int gemm_blocks = (N + GBM - 1) / GBM;
    int agg_blocks = (N + 3) / 4;

    // layer 1
    gemm_mfma_kernel<<<gemm_blocks, 256, 0, stream>>>(x, wf1h, wf1l, m, N);
    agg_kernel<<<agg_blocks, 256, 0, stream>>>((const unsigned int*)m, rowstart, csr,
                                               dinv, b1, h, N);
    // layer 2
    gemm_mfma_kernel<<<gemm_blocks, 256, 0, stream>>>(h, wf2h, wf2l, m, N);
    agg_kernel<<<agg_blocks, 256, 0, stream>>>((const unsigned int*)m, rowstart, csr,
                                               dinv, b2, h, N);

    // global max pool
    int pblocks = (N + POOL_NODES - 1) / POOL_NODES;
    pool_kernel<<<pblocks, 128, 0, stream>>>(h, batch, g, N);

    // MLP head + log_softmax
    mlp_kernel<<<G, 128, 0, stream>>>(g, W3, b3, W4, b4, (float*)d_out);
}

// Round 4
// 272.018 us; speedup vs baseline: 1.5099x; 1.0546x over previous
//
#include <hip/hip_runtime.h>
#include <hip/hip_bf16.h>
#include <math.h>

// ---------------- constants ----------------
#define HDIM 128
#define SCAN_B 256

typedef short bfrag __attribute__((ext_vector_type(8)));   // 8 bf16 (4 VGPRs)
typedef float f32x4 __attribute__((ext_vector_type(4)));   // 4 fp32 acc

__device__ inline unsigned short f2bf_rne(float x) {
    unsigned u = __float_as_uint(x);
    u = (u + 0x7fffu + ((u >> 16) & 1u)) >> 16;
    return (unsigned short)u;
}
__device__ inline float bf_lo(unsigned u) { return __uint_as_float(u << 16); }
__device__ inline float bf_hi(unsigned u) { return __uint_as_float(u & 0xffff0000u); }

// ---------------- degree count ----------------
__global__ __launch_bounds__(256) void count_kernel(const int* __restrict__ dst,
                                                    int* __restrict__ cnt, int E) {
    int e = blockIdx.x * 256 + threadIdx.x;
    if (e < E) atomicAdd(&cnt[dst[e]], 1);
}

// ---------------- scan phase 1 (+ dinv, which only needs cnt) ----------------
__global__ __launch_bounds__(SCAN_B) void scan1_kernel(const int* __restrict__ cnt,
                                                       int* __restrict__ rowstart,
                                                       int* __restrict__ sums,
                                                       float* __restrict__ dinv, int n) {
    __shared__ int s[SCAN_B];
    int t = threadIdx.x;
    int idx = blockIdx.x * SCAN_B + t;
    int v = (idx < n) ? cnt[idx] : 0;
    if (idx < n) dinv[idx] = rsqrtf((float)(v + 1));   // +1 self-loop
    s[t] = v;
    __syncthreads();
    for (int off = 1; off < SCAN_B; off <<= 1) {
        int x = (t >= off) ? s[t - off] : 0;
        __syncthreads();
        s[t] += x;
        __syncthreads();
    }
    if (idx < n) rowstart[idx] = s[t];
    if (t == SCAN_B - 1) sums[blockIdx.x] = s[t];
}

__global__ __launch_bounds__(SCAN_B) void scan2_kernel(int* __restrict__ sums, int nb) {
    __shared__ int s[SCAN_B];
    int t = threadIdx.x;
    int v = (t < nb) ? sums[t] : 0;
    s[t] = v;
    __syncthreads();
    for (int off = 1; off < SCAN_B; off <<= 1) {
        int x = (t >= off) ? s[t - off] : 0;
        __syncthreads();
        s[t] += x;
        __syncthreads();
    }
    if (t < nb) sums[t] = s[t] - v;
}

__global__ __launch_bounds__(SCAN_B) void scan3_kernel(const int* __restrict__ cnt,
                                                       int* __restrict__ rowstart,
                                                       const int* __restrict__ sums,
                                                       int n, int E) {
    int idx = blockIdx.x * SCAN_B + threadIdx.x;
    if (idx < n) {
        int incl = rowstart[idx];
        rowstart[idx] = incl - cnt[idx] + sums[blockIdx.x];
    }
    if (idx == 0) rowstart[n] = E;
}

// ---------------- CSR fill: fused (src, weight) pairs ----------------
__global__ __launch_bounds__(256) void fill_kernel(const int* __restrict__ srcv,
                                                   const int* __restrict__ dstv,
                                                   const int* __restrict__ rowstart,
                                                   int* __restrict__ cursor,
                                                   const float* __restrict__ dinv,
                                                   int2* __restrict__ csr, int E) {
    int e = blockIdx.x * 256 + threadIdx.x;
    if (e < E) {
        int s = srcv[e], d = dstv[e];
        int slot = atomicAdd(&cursor[d], 1);
        int pos = rowstart[d] + slot;
        csr[pos] = make_int2(s, __float_as_int(dinv[s] * dinv[d]));
    }
}

// ---------------- W -> fragment-ordered bf16 hi/lo, COLUMN-PERMUTED ----------------
// Physical MFMA output slot (tile nt, col-in-tile lm) is fed logical column
// n_l = lm*8 + nt, so each lane's 8 outputs are logically consecutive columns.
// Handles both W1 and W2 in one launch (blockIdx >= 64 -> W2).
__global__ __launch_bounds__(256) void wfrag_kernel(const float* __restrict__ W1,
                                                    const float* __restrict__ W2,
                                                    unsigned short* __restrict__ w1h,
                                                    unsigned short* __restrict__ w1l,
                                                    unsigned short* __restrict__ w2h,
                                                    unsigned short* __restrict__ w2l) {
    int b = blockIdx.x;
    const float* W = (b < 64) ? W1 : W2;
    unsigned short* whi = (b < 64) ? w1h : w2h;
    unsigned short* wlo = (b < 64) ? w1l : w2l;
    int idx = (b & 63) * 256 + threadIdx.x;     // 0..16383
    int k = idx >> 7;
    int n = idx & 127;
    int kt = k >> 5, q = (k >> 3) & 3, j = k & 7;
    int lm = n >> 3, nt = n & 7;
    int lane = q * 16 + lm;
    int o = ((kt * 8 + nt) * 64 + lane) * 8 + j;
    float x = W[idx];
    unsigned short hb = f2bf_rne(x);
    float hf = __uint_as_float(((unsigned)hb) << 16);
    unsigned short lb = f2bf_rne(x - hf);
    whi[o] = hb;
    wlo[o] = lb;
}

// ---------------- MFMA GEMM (fp32 A): C_bf16 = A_f32 @ W, split 3-MFMA ----------------
#define GBM 128
__global__ __launch_bounds__(256) void gemm_f32_kernel(
        const float* __restrict__ A,
        const unsigned short* __restrict__ whi,
        const unsigned short* __restrict__ wlo,
        unsigned short* __restrict__ C, int Nrows) {
    int tid = threadIdx.x;
    int w = tid >> 6, L = tid & 63;
    int lm = L & 15, lq = L >> 4;
    int row0 = blockIdx.x * GBM + w * 32;

    f32x4 acc[2][8];
#pragma unroll
    for (int mt = 0; mt < 2; ++mt)
#pragma unroll
        for (int nt = 0; nt < 8; ++nt) acc[mt][nt] = (f32x4)(0.f);

#pragma unroll
    for (int kt = 0; kt < 4; ++kt) {
        bfrag ah[2], al[2];
#pragma unroll
        for (int mt = 0; mt < 2; ++mt) {
            int gr = row0 + mt * 16 + lm;
            float4 v0 = make_float4(0.f, 0.f, 0.f, 0.f);
            float4 v1 = v0;
            if (gr < Nrows) {
                const float* p = &A[(size_t)gr * HDIM + kt * 32 + lq * 8];
                v0 = *(const float4*)p;
                v1 = *(const float4*)(p + 4);
            }
            float xv[8] = {v0.x, v0.y, v0.z, v0.w, v1.x, v1.y, v1.z, v1.w};
            bfrag hh, ll;
#pragma unroll
            for (int j = 0; j < 8; ++j) {
                float x = xv[j];
                unsigned short hb = f2bf_rne(x);
                float hf = __uint_as_float(((unsigned)hb) << 16);
                unsigned short lb = f2bf_rne(x - hf);
                hh[j] = (short)hb;
                ll[j] = (short)lb;
            }
            ah[mt] = hh;
            al[mt] = ll;
        }
#pragma unroll
        for (int nt = 0; nt < 8; ++nt) {
            int o = ((kt * 8 + nt) * 64 + L) * 8;
            bfrag wh = *(const bfrag*)&whi[o];
            bfrag wl = *(const bfrag*)&wlo[o];
#pragma unroll
            for (int mt = 0; mt < 2; ++mt) {
                acc[mt][nt] = __builtin_amdgcn_mfma_f32_16x16x32_bf16(ah[mt], wh, acc[mt][nt], 0, 0, 0);
                acc[mt][nt] = __builtin_amdgcn_mfma_f32_16x16x32_bf16(al[mt], wh, acc[mt][nt], 0, 0, 0);
                acc[mt][nt] = __builtin_amdgcn_mfma_f32_16x16x32_bf16(ah[mt], wl, acc[mt][nt], 0, 0, 0);
            }
        }
    }

    // epilogue: lane's 8 outputs = logical cols lm*8..lm*8+7 -> one 16B store
#pragma unroll
    for (int mt = 0; mt < 2; ++mt)
#pragma unroll
        for (int i = 0; i < 4; ++i) {
            int gr = row0 + mt * 16 + lq * 4 + i;
            if (gr < Nrows) {
                bfrag e;
#pragma unroll
                for (int nt = 0; nt < 8; ++nt) e[nt] = (short)f2bf_rne(acc[mt][nt][i]);
                *(bfrag*)&C[(size_t)gr * HDIM + lm * 8] = e;
            }
        }
}

// ---------------- MFMA GEMM (bf16 A): A exact bf16 -> 2 MFMAs per tile ----------------
__global__ __launch_bounds__(256) void gemm_bf16_kernel(
        const unsigned short* __restrict__ A16,
        const unsigned short* __restrict__ whi,
        const unsigned short* __restrict__ wlo,
        unsigned short* __restrict__ C, int Nrows) {
    int tid = threadIdx.x;
    int w = tid >> 6, L = tid & 63;
    int lm = L & 15, lq = L >> 4;
    int row0 = blockIdx.x * GBM + w * 32;

    f32x4 acc[2][8];
#pragma unroll
    for (int mt = 0; mt < 2; ++mt)
#pragma unroll
        for (int nt = 0; nt < 8; ++nt) acc[mt][nt] = (f32x4)(0.f);

#pragma unroll
    for (int kt = 0; kt < 4; ++kt) {
        bfrag ah[2];
#pragma unroll
        for (int mt = 0; mt < 2; ++mt) {
            int gr = row0 + mt * 16 + lm;
            bfrag v = (bfrag)(short)0;
            if (gr < Nrows) v = *(const bfrag*)&A16[(size_t)gr * HDIM + kt * 32 + lq * 8];
            ah[mt] = v;
        }
#pragma unroll
        for (int nt = 0; nt < 8; ++nt) {
            int o = ((kt * 8 + nt) * 64 + L) * 8;
            bfrag wh = *(const bfrag*)&whi[o];
            bfrag wl = *(const bfrag*)&wlo[o];
#pragma unroll
            for (int mt = 0; mt < 2; ++mt) {
                acc[mt][nt] = __builtin_amdgcn_mfma_f32_16x16x32_bf16(ah[mt], wh, acc[mt][nt], 0, 0, 0);
                acc[mt][nt] = __builtin_amdgcn_mfma_f32_16x16x32_bf16(ah[mt], wl, acc[mt][nt], 0, 0, 0);
            }
        }
    }

#pragma unroll
    for (int mt = 0; mt < 2; ++mt)
#pragma unroll
        for (int i = 0; i < 4; ++i) {
            int gr = row0 + mt * 16 + lq * 4 + i;
            if (gr < Nrows) {
                bfrag e;
#pragma unroll
                for (int nt = 0; nt < 8; ++nt) e[nt] = (short)f2bf_rne(acc[mt][nt][i]);
                *(bfrag*)&C[(size_t)gr * HDIM + lm * 8] = e;
            }
        }
}

// ---------------- gather core for aggregation (unroll 8 / 4 / 1) ----------------
__device__ inline void agg_gather(const unsigned int* __restrict__ m2,
                                  const int2* __restrict__ csr,
                                  int p, int pend, int lane,
                                  float& ax, float& ay) {
    for (; p + 8 <= pend; p += 8) {
        int2 e0 = csr[p], e1 = csr[p + 1], e2 = csr[p + 2], e3 = csr[p + 3];
        int2 e4 = csr[p + 4], e5 = csr[p + 5], e6 = csr[p + 6], e7 = csr[p + 7];
        unsigned u0 = m2[(size_t)e0.x * 64 + lane];
        unsigned u1 = m2[(size_t)e1.x * 64 + lane];
        unsigned u2 = m2[(size_t)e2.x * 64 + lane];
        unsigned u3 = m2[(size_t)e3.x * 64 + lane];
        unsigned u4 = m2[(size_t)e4.x * 64 + lane];
        unsigned u5 = m2[(size_t)e5.x * 64 + lane];
        unsigned u6 = m2[(size_t)e6.x * 64 + lane];
        unsigned u7 = m2[(size_t)e7.x * 64 + lane];
        float w0 = __int_as_float(e0.y), w1 = __int_as_float(e1.y);
        float w2 = __int_as_float(e2.y), w3 = __int_as_float(e3.y);
        float w4 = __int_as_float(e4.y), w5 = __int_as_float(e5.y);
        float w6 = __int_as_float(e6.y), w7 = __int_as_float(e7.y);
        ax = fmaf(w0, bf_lo(u0), ax); ay = fmaf(w0, bf_hi(u0), ay);
        ax = fmaf(w1, bf_lo(u1), ax); ay = fmaf(w1, bf_hi(u1), ay);
        ax = fmaf(w2, bf_lo(u2), ax); ay = fmaf(w2, bf_hi(u2), ay);
        ax = fmaf(w3, bf_lo(u3), ax); ay = fmaf(w3, bf_hi(u3), ay);
        ax = fmaf(w4, bf_lo(u4), ax); ay = fmaf(w4, bf_hi(u4), ay);
        ax = fmaf(w5, bf_lo(u5), ax); ay = fmaf(w5, bf_hi(u5), ay);
        ax = fmaf(w6, bf_lo(u6), ax); ay = fmaf(w6, bf_hi(u6), ay);
        ax = fmaf(w7, bf_lo(u7), ax); ay = fmaf(w7, bf_hi(u7), ay);
    }
    if (p + 4 <= pend) {
        int2 e0 = csr[p], e1 = csr[p + 1], e2 = csr[p + 2], e3 = csr[p + 3];
        unsigned u0 = m2[(size_t)e0.x * 64 + lane];
        unsigned u1 = m2[(size_t)e1.x * 64 + lane];
        unsigned u2 = m2[(size_t)e2.x * 64 + lane];
        unsigned u3 = m2[(size_t)e3.x * 64 + lane];
        float w0 = __int_as_float(e0.y), w1 = __int_as_float(e1.y);
        float w2 = __int_as_float(e2.y), w3 = __int_as_float(e3.y);
        ax = fmaf(w0, bf_lo(u0), ax); ay = fmaf(w0, bf_hi(u0), ay);
        ax = fmaf(w1, bf_lo(u1), ax); ay = fmaf(w1, bf_hi(u1), ay);
        ax = fmaf(w2, bf_lo(u2), ax); ay = fmaf(w2, bf_hi(u2), ay);
        ax = fmaf(w3, bf_lo(u3), ax); ay = fmaf(w3, bf_hi(u3), ay);
        p += 4;
    }
    for (; p < pend; ++p) {
        int2 e = csr[p];
        unsigned u = m2[(size_t)e.x * 64 + lane];
        float wgt = __int_as_float(e.y);
        ax = fmaf(wgt, bf_lo(u), ax);
        ay = fmaf(wgt, bf_hi(u), ay);
    }
}

// ---------------- agg layer 1: wave/node, bf16-packed output ----------------
__global__ __launch_bounds__(256) void agg_kernel(const unsigned int* __restrict__ m2,
                                                  const int* __restrict__ rowstart,
                                                  const int2* __restrict__ csr,
                                                  const float* __restrict__ dinv,
                                                  const float* __restrict__ bias,
                                                  unsigned int* __restrict__ out, int n) {
    int wid = threadIdx.x >> 6;
    int lane = threadIdx.x & 63;
    int node = blockIdx.x * 4 + wid;
    if (node >= n) return;
    float ds = dinv[node];
    float wself = ds * ds;
    unsigned v = m2[(size_t)node * 64 + lane];
    float ax = bf_lo(v) * wself;
    float ay = bf_hi(v) * wself;
    agg_gather(m2, csr, rowstart[node], rowstart[node + 1], lane, ax, ay);
    float2 bv = ((const float2*)bias)[lane];
    ax = fmaxf(ax + bv.x, 0.f);
    ay = fmaxf(ay + bv.y, 0.f);
    out[(size_t)node * 64 + lane] =
        ((unsigned)f2bf_rne(ay) << 16) | (unsigned)f2bf_rne(ax);
}

// ---------------- agg layer 2 fused with global max pool ----------------
// batch is sorted; block's 4 consecutive nodes usually share a graph ->
// per-block run-max then ~1 atomicMax per column per block.
__global__ __launch_bounds__(256) void agg_pool_kernel(const unsigned int* __restrict__ m2,
                                                       const int* __restrict__ rowstart,
                                                       const int2* __restrict__ csr,
                                                       const float* __restrict__ dinv,
                                                       const float* __restrict__ bias,
                                                       const int* __restrict__ batch,
                                                       unsigned int* __restrict__ g, int n) {
    __shared__ float smx[4][HDIM];
    __shared__ int sgid[4];
    int wid = threadIdx.x >> 6;
    int lane = threadIdx.x & 63;
    int node = blockIdx.x * 4 + wid;
    bool valid = node < n;
    float ax = 0.f, ay = 0.f;
    if (valid) {
        float ds = dinv[node];
        float wself = ds * ds;
        unsigned v = m2[(size_t)node * 64 + lane];
        ax = bf_lo(v) * wself;
        ay = bf_hi(v) * wself;
        agg_gather(m2, csr, rowstart[node], rowstart[node + 1], lane, ax, ay);
        float2 bv = ((const float2*)bias)[lane];
        ax = fmaxf(ax + bv.x, 0.f);
        ay = fmaxf(ay + bv.y, 0.f);
    }
    smx[wid][lane * 2] = ax;
    smx[wid][lane * 2 + 1] = ay;
    if (lane == 0) sgid[wid] = valid ? batch[node] : -1;
    __syncthreads();
    if (threadIdx.x < HDIM) {
        int c = threadIdx.x;
        int curg = -1;
        float run = 0.f;
#pragma unroll
        for (int r = 0; r < 4; ++r) {
            int gg = sgid[r];
            if (gg < 0) continue;
            if (gg != curg) {
                if (curg >= 0) atomicMax(&g[curg * HDIM + c], __float_as_uint(run));
                curg = gg;
                run = smx[r][c];
            } else {
                run = fmaxf(run, smx[r][c]);
            }
        }
        if (curg >= 0) atomicMax(&g[curg * HDIM + c], __float_as_uint(run));
    }
}

// ---------------- MLP head + log_softmax ----------------
__global__ __launch_bounds__(128) void mlp_kernel(const unsigned int* __restrict__ gbits,
                                                  const float* __restrict__ W3,
                                                  const float* __restrict__ b3,
                                                  const float* __restrict__ W4,
                                                  const float* __restrict__ b4,
                                                  float* __restrict__ out) {
    __shared__ float gs[HDIM];
    __shared__ float r0[HDIM];
    __shared__ float r1[HDIM];
    int j = threadIdx.x;
    int b = blockIdx.x;
    gs[j] = __uint_as_float(gbits[b * HDIM + j]);
    __syncthreads();
    float acc = b3[j];
#pragma unroll 8
    for (int k = 0; k < HDIM; ++k) acc = fmaf(gs[k], W3[k * HDIM + j], acc);
    float z = fmaxf(acc, 0.f);
    r0[j] = z * W4[j * 2 + 0];
    r1[j] = z * W4[j * 2 + 1];
    __syncthreads();
    for (int off = 64; off > 0; off >>= 1) {
        if (j < off) {
            r0[j] += r0[j + off];
            r1[j] += r1[j + off];
        }
        __syncthreads();
    }
    if (j == 0) {
        float l0 = r0[0] + b4[0];
        float l1 = r1[0] + b4[1];
        float mx = fmaxf(l0, l1);
        float lse = mx + logf(expf(l0 - mx) + expf(l1 - mx));
        out[b * 2 + 0] = l0 - lse;
        out[b * 2 + 1] = l1 - lse;
    }
}

extern "C" void kernel_launch(void* const* d_in, const int* in_sizes, int n_in,
                              void* d_out, int out_size, void* d_ws, size_t ws_size,
                              hipStream_t stream) {
    const float* x  = (const float*)d_in[0];
    const float* W1 = (const float*)d_in[1];
    const float* b1 = (const float*)d_in[2];
    const float* W2 = (const float*)d_in[3];
    const float* b2 = (const float*)d_in[4];
    const float* W3 = (const float*)d_in[5];
    const float* b3 = (const float*)d_in[6];
    const float* W4 = (const float*)d_in[7];
    const float* b4 = (const float*)d_in[8];
    const int* ei    = (const int*)d_in[9];
    const int* batch = (const int*)d_in[10];

    const int N = in_sizes[0] / HDIM;   // 50000
    const int E = in_sizes[9] / 2;      // 640000
    const int G = out_size / 2;         // 64
    const int* src = ei;
    const int* dst = ei + E;

    // ---- workspace layout (all offsets 16B-aligned) ----
    const int Nr = ((N + 63) / 64) * 64;
    char* wsb = (char*)d_ws;
    size_t o = 0;
    int* cnt = (int*)(wsb + o);            o += (size_t)Nr * 4;
    int* cursor = (int*)(wsb + o);         o += (size_t)Nr * 4;
    unsigned int* g = (unsigned int*)(wsb + o); o += (size_t)G * HDIM * 4;
    size_t zero_bytes = o;                 // cnt + cursor + g zeroed together
    int* sums = (int*)(wsb + o);           o += 256 * 4;
    int* rowstart = (int*)(wsb + o);       o += (size_t)(Nr + 64) * 4;
    float* dinv = (float*)(wsb + o);       o += (size_t)Nr * 4;
    int2* csr = (int2*)(wsb + o);          o += (size_t)E * 8;
    unsigned short* wf1h = (unsigned short*)(wsb + o); o += (size_t)HDIM * HDIM * 2;
    unsigned short* wf1l = (unsigned short*)(wsb + o); o += (size_t)HDIM * HDIM * 2;
    unsigned short* wf2h = (unsigned short*)(wsb + o); o += (size_t)HDIM * HDIM * 2;
    unsigned short* wf2l = (unsigned short*)(wsb + o); o += (size_t)HDIM * HDIM * 2;
    unsigned short* m = (unsigned short*)(wsb + o);    o += (size_t)Nr * HDIM * 2;
    unsigned int* h = (unsigned int*)(wsb + o);        o += (size_t)Nr * 64 * 4;
    (void)ws_size; (void)n_in;

    hipMemsetAsync(d_ws, 0, zero_bytes, stream);

    int eblocks = (E + 255) / 256;
    int nb = (N + SCAN_B - 1) / SCAN_B;

    count_kernel<<<eblocks, 256, 0, stream>>>(dst, cnt, E);
    scan1_kernel<<<nb, SCAN_B, 0, stream>>>(cnt, rowstart, sums, dinv, N);
    scan2_kernel<<<1, SCAN_B, 0, stream>>>(sums, nb);
    scan3_kernel<<<nb, SCAN_B, 0, stream>>>(cnt, rowstart, sums, N, E);
    fill_kernel<<<eblocks, 256, 0, stream>>>(src, dst, rowstart, cursor, dinv, csr, E);

    wfrag_kernel<<<128, 256, 0, stream>>>(W1, W2, wf1h, wf1l, wf2h, wf2l);

    int gemm_blocks = (N + GBM - 1) / GBM;
    int agg_blocks = (N + 3) / 4;

    // layer 1: m = bf16(x@W1); h = bf16(relu(agg(m)+b1))
    gemm_f32_kernel<<<gemm_blocks, 256, 0, stream>>>(x, wf1h, wf1l, m, N);
    agg_kernel<<<agg_blocks, 256, 0, stream>>>((const unsigned int*)m, rowstart, csr,
                                               dinv, b1, h, N);
    // layer 2: m = bf16(h@W2); g = segmax(relu(agg(m)+b2))  [pool fused]
    gemm_bf16_kernel<<<gemm_blocks, 256, 0, stream>>>((const unsigned short*)h,
                                                      wf2h, wf2l, m, N);
    agg_pool_kernel<<<agg_blocks, 256, 0, stream>>>((const unsigned int*)m, rowstart, csr,
                                                    dinv, b2, batch, g, N);

    // MLP head + log_softmax
    mlp_kernel<<<G, 128, 0, stream>>>(g, W3, b3, W4, b4, (float*)d_out);
}

// Round 5
// 254.621 us; speedup vs baseline: 1.6130x; 1.0683x over previous
//
#include <hip/hip_runtime.h>
#include <hip/hip_bf16.h>
#include <math.h>

// ---------------- constants ----------------
#define HDIM 128
#define SCAN_B 256

typedef short bfrag __attribute__((ext_vector_type(8)));   // 8 bf16 (4 VGPRs)
typedef float f32x4 __attribute__((ext_vector_type(4)));   // 4 fp32 acc

__device__ inline unsigned short f2bf_rne(float x) {
    unsigned u = __float_as_uint(x);
    u = (u + 0x7fffu + ((u >> 16) & 1u)) >> 16;
    return (unsigned short)u;
}
__device__ inline float bf_lo(unsigned u) { return __uint_as_float(u << 16); }
__device__ inline float bf_hi(unsigned u) { return __uint_as_float(u & 0xffff0000u); }
__device__ inline unsigned bf_pack(float lo, float hi) {
    return ((unsigned)f2bf_rne(hi) << 16) | (unsigned)f2bf_rne(lo);
}

// ---------------- degree count ----------------
__global__ __launch_bounds__(256) void count_kernel(const int* __restrict__ dst,
                                                    int* __restrict__ cnt, int E) {
    int e = blockIdx.x * 256 + threadIdx.x;
    if (e < E) atomicAdd(&cnt[dst[e]], 1);
}

// ---------------- scan phase 1 (+ dinv) ----------------
__global__ __launch_bounds__(SCAN_B) void scan1_kernel(const int* __restrict__ cnt,
                                                       int* __restrict__ rowstart,
                                                       int* __restrict__ sums,
                                                       float* __restrict__ dinv, int n) {
    __shared__ int s[SCAN_B];
    int t = threadIdx.x;
    int idx = blockIdx.x * SCAN_B + t;
    int v = (idx < n) ? cnt[idx] : 0;
    if (idx < n) dinv[idx] = rsqrtf((float)(v + 1));   // +1 self-loop
    s[t] = v;
    __syncthreads();
    for (int off = 1; off < SCAN_B; off <<= 1) {
        int x = (t >= off) ? s[t - off] : 0;
        __syncthreads();
        s[t] += x;
        __syncthreads();
    }
    if (idx < n) rowstart[idx] = s[t];
    if (t == SCAN_B - 1) sums[blockIdx.x] = s[t];
}

__global__ __launch_bounds__(SCAN_B) void scan2_kernel(int* __restrict__ sums, int nb) {
    __shared__ int s[SCAN_B];
    int t = threadIdx.x;
    int v = (t < nb) ? sums[t] : 0;
    s[t] = v;
    __syncthreads();
    for (int off = 1; off < SCAN_B; off <<= 1) {
        int x = (t >= off) ? s[t - off] : 0;
        __syncthreads();
        s[t] += x;
        __syncthreads();
    }
    if (t < nb) sums[t] = s[t] - v;
}

// writes rowstart (exclusive) AND initializes cursor = rowstart (no memset needed)
__global__ __launch_bounds__(SCAN_B) void scan3_kernel(const int* __restrict__ cnt,
                                                       int* __restrict__ rowstart,
                                                       const int* __restrict__ sums,
                                                       int* __restrict__ cursor,
                                                       int n, int E) {
    int idx = blockIdx.x * SCAN_B + threadIdx.x;
    if (idx < n) {
        int incl = rowstart[idx];
        int excl = incl - cnt[idx] + sums[blockIdx.x];
        rowstart[idx] = excl;
        cursor[idx] = excl;
    }
    if (idx == 0) rowstart[n] = E;
}

// ---------------- CSR fill: src only (weights gathered at agg time) ----------------
__global__ __launch_bounds__(256) void fill_kernel(const int* __restrict__ srcv,
                                                   const int* __restrict__ dstv,
                                                   int* __restrict__ cursor,
                                                   int* __restrict__ csr, int E) {
    int e = blockIdx.x * 256 + threadIdx.x;
    if (e < E) {
        int d = dstv[e];
        int pos = atomicAdd(&cursor[d], 1);
        csr[pos] = srcv[e];
    }
}

// ---------------- W -> fragment-ordered bf16 hi/lo, COLUMN-PERMUTED ----------------
// Physical MFMA output slot (tile nt, col-in-tile lm) is fed logical column
// n_l = lm*8 + nt, so each lane's 8 outputs are logically consecutive columns.
__global__ __launch_bounds__(256) void wfrag_kernel(const float* __restrict__ W1,
                                                    const float* __restrict__ W2,
                                                    unsigned short* __restrict__ w1h,
                                                    unsigned short* __restrict__ w1l,
                                                    unsigned short* __restrict__ w2h,
                                                    unsigned short* __restrict__ w2l) {
    int b = blockIdx.x;
    const float* W = (b < 64) ? W1 : W2;
    unsigned short* whi = (b < 64) ? w1h : w2h;
    unsigned short* wlo = (b < 64) ? w1l : w2l;
    int idx = (b & 63) * 256 + threadIdx.x;     // 0..16383
    int k = idx >> 7;
    int n = idx & 127;
    int kt = k >> 5, q = (k >> 3) & 3, j = k & 7;
    int lm = n >> 3, nt = n & 7;
    int lane = q * 16 + lm;
    int o = ((kt * 8 + nt) * 64 + lane) * 8 + j;
    float x = W[idx];
    unsigned short hb = f2bf_rne(x);
    float hf = __uint_as_float(((unsigned)hb) << 16);
    unsigned short lb = f2bf_rne(x - hf);
    whi[o] = hb;
    wlo[o] = lb;
}

// ---------------- MFMA GEMM (fp32 A): 64-row tiles, split 3-MFMA ----------------
#define GBM 64
__global__ __launch_bounds__(256) void gemm_f32_kernel(
        const float* __restrict__ A,
        const unsigned short* __restrict__ whi,
        const unsigned short* __restrict__ wlo,
        unsigned short* __restrict__ C, int Nrows) {
    int tid = threadIdx.x;
    int w = tid >> 6, L = tid & 63;
    int lm = L & 15, lq = L >> 4;
    int row0 = blockIdx.x * GBM + w * 16;

    f32x4 acc[8];
#pragma unroll
    for (int nt = 0; nt < 8; ++nt) acc[nt] = (f32x4)(0.f);

#pragma unroll
    for (int kt = 0; kt < 4; ++kt) {
        int gr = row0 + lm;
        float4 v0 = make_float4(0.f, 0.f, 0.f, 0.f);
        float4 v1 = v0;
        if (gr < Nrows) {
            const float* p = &A[(size_t)gr * HDIM + kt * 32 + lq * 8];
            v0 = *(const float4*)p;
            v1 = *(const float4*)(p + 4);
        }
        float xv[8] = {v0.x, v0.y, v0.z, v0.w, v1.x, v1.y, v1.z, v1.w};
        bfrag ah, al;
#pragma unroll
        for (int j = 0; j < 8; ++j) {
            float x = xv[j];
            unsigned short hb = f2bf_rne(x);
            float hf = __uint_as_float(((unsigned)hb) << 16);
            unsigned short lb = f2bf_rne(x - hf);
            ah[j] = (short)hb;
            al[j] = (short)lb;
        }
#pragma unroll
        for (int nt = 0; nt < 8; ++nt) {
            int o = ((kt * 8 + nt) * 64 + L) * 8;
            bfrag wh = *(const bfrag*)&whi[o];
            bfrag wl = *(const bfrag*)&wlo[o];
            acc[nt] = __builtin_amdgcn_mfma_f32_16x16x32_bf16(ah, wh, acc[nt], 0, 0, 0);
            acc[nt] = __builtin_amdgcn_mfma_f32_16x16x32_bf16(al, wh, acc[nt], 0, 0, 0);
            acc[nt] = __builtin_amdgcn_mfma_f32_16x16x32_bf16(ah, wl, acc[nt], 0, 0, 0);
        }
    }

#pragma unroll
    for (int i = 0; i < 4; ++i) {
        int gr = row0 + lq * 4 + i;
        if (gr < Nrows) {
            bfrag e;
#pragma unroll
            for (int nt = 0; nt < 8; ++nt) e[nt] = (short)f2bf_rne(acc[nt][i]);
            *(bfrag*)&C[(size_t)gr * HDIM + lm * 8] = e;
        }
    }
}

// ---------------- MFMA GEMM (bf16 A): 2 MFMAs per tile ----------------
__global__ __launch_bounds__(256) void gemm_bf16_kernel(
        const unsigned short* __restrict__ A16,
        const unsigned short* __restrict__ whi,
        const unsigned short* __restrict__ wlo,
        unsigned short* __restrict__ C, int Nrows) {
    int tid = threadIdx.x;
    int w = tid >> 6, L = tid & 63;
    int lm = L & 15, lq = L >> 4;
    int row0 = blockIdx.x * GBM + w * 16;

    f32x4 acc[8];
#pragma unroll
    for (int nt = 0; nt < 8; ++nt) acc[nt] = (f32x4)(0.f);

#pragma unroll
    for (int kt = 0; kt < 4; ++kt) {
        int gr = row0 + lm;
        bfrag ah = (bfrag)(short)0;
        if (gr < Nrows) ah = *(const bfrag*)&A16[(size_t)gr * HDIM + kt * 32 + lq * 8];
#pragma unroll
        for (int nt = 0; nt < 8; ++nt) {
            int o = ((kt * 8 + nt) * 64 + L) * 8;
            bfrag wh = *(const bfrag*)&whi[o];
            bfrag wl = *(const bfrag*)&wlo[o];
            acc[nt] = __builtin_amdgcn_mfma_f32_16x16x32_bf16(ah, wh, acc[nt], 0, 0, 0);
            acc[nt] = __builtin_amdgcn_mfma_f32_16x16x32_bf16(ah, wl, acc[nt], 0, 0, 0);
        }
    }

#pragma unroll
    for (int i = 0; i < 4; ++i) {
        int gr = row0 + lq * 4 + i;
        if (gr < Nrows) {
            bfrag e;
#pragma unroll
            for (int nt = 0; nt < 8; ++nt) e[nt] = (short)f2bf_rne(acc[nt][i]);
            *(bfrag*)&C[(size_t)gr * HDIM + lm * 8] = e;
        }
    }
}

// ---------------- quarter-wave gather core: 16 lanes x uint4 per node ----------------
// acc[8] accumulates Sum_e dinv[src]*m[src] for features 8t..8t+7 (t = lane&15).
__device__ inline void qgather(const uint4* __restrict__ m4,
                               const int* __restrict__ csr,
                               const float* __restrict__ dinv,
                               int p, int pend, int t, float* acc) {
    int s_next = (p < pend) ? csr[p] : 0;
    while (p < pend) {
        int s = s_next;
        float w = dinv[s];
        uint4 u = m4[(size_t)s * 16 + t];
        ++p;
        if (p < pend) s_next = csr[p];
        acc[0] = fmaf(w, bf_lo(u.x), acc[0]);
        acc[1] = fmaf(w, bf_hi(u.x), acc[1]);
        acc[2] = fmaf(w, bf_lo(u.y), acc[2]);
        acc[3] = fmaf(w, bf_hi(u.y), acc[3]);
        acc[4] = fmaf(w, bf_lo(u.z), acc[4]);
        acc[5] = fmaf(w, bf_hi(u.z), acc[5]);
        acc[6] = fmaf(w, bf_lo(u.w), acc[6]);
        acc[7] = fmaf(w, bf_hi(u.w), acc[7]);
    }
}

// ---------------- agg layer 1: 4 nodes/wave, bf16-packed output ----------------
__global__ __launch_bounds__(256) void agg_kernel(const uint4* __restrict__ m4,
                                                  const int* __restrict__ rowstart,
                                                  const int* __restrict__ csr,
                                                  const float* __restrict__ dinv,
                                                  const float* __restrict__ bias,
                                                  uint4* __restrict__ out, int n) {
    int t = threadIdx.x & 15;
    int node = blockIdx.x * 16 + (threadIdx.x >> 4);
    if (node >= n) return;
    float dd = dinv[node];
    float acc[8];
    {   // self term, weight dinv[node] (dinv[dst] factored out of the sum)
        uint4 u = m4[(size_t)node * 16 + t];
        acc[0] = dd * bf_lo(u.x); acc[1] = dd * bf_hi(u.x);
        acc[2] = dd * bf_lo(u.y); acc[3] = dd * bf_hi(u.y);
        acc[4] = dd * bf_lo(u.z); acc[5] = dd * bf_hi(u.z);
        acc[6] = dd * bf_lo(u.w); acc[7] = dd * bf_hi(u.w);
    }
    qgather(m4, csr, dinv, rowstart[node], rowstart[node + 1], t, acc);
    float4 b0 = *(const float4*)&bias[t * 8];
    float4 b1 = *(const float4*)&bias[t * 8 + 4];
    uint4 o;
    o.x = bf_pack(fmaxf(fmaf(dd, acc[0], b0.x), 0.f), fmaxf(fmaf(dd, acc[1], b0.y), 0.f));
    o.y = bf_pack(fmaxf(fmaf(dd, acc[2], b0.z), 0.f), fmaxf(fmaf(dd, acc[3], b0.w), 0.f));
    o.z = bf_pack(fmaxf(fmaf(dd, acc[4], b1.x), 0.f), fmaxf(fmaf(dd, acc[5], b1.y), 0.f));
    o.w = bf_pack(fmaxf(fmaf(dd, acc[6], b1.z), 0.f), fmaxf(fmaf(dd, acc[7], b1.w), 0.f));
    out[(size_t)node * 16 + t] = o;
}

// ---------------- agg layer 2 fused with global max pool ----------------
__global__ __launch_bounds__(256) void agg_pool_kernel(const uint4* __restrict__ m4,
                                                       const int* __restrict__ rowstart,
                                                       const int* __restrict__ csr,
                                                       const float* __restrict__ dinv,
                                                       const float* __restrict__ bias,
                                                       const int* __restrict__ batch,
                                                       unsigned int* __restrict__ g, int n) {
    __shared__ float smx[16][HDIM];
    __shared__ int sgid[16];
    int t = threadIdx.x & 15;
    int nl = threadIdx.x >> 4;              // node-in-block 0..15
    int node = blockIdx.x * 16 + nl;
    bool valid = node < n;
    if (valid) {
        float dd = dinv[node];
        float acc[8];
        uint4 u = m4[(size_t)node * 16 + t];
        acc[0] = dd * bf_lo(u.x); acc[1] = dd * bf_hi(u.x);
        acc[2] = dd * bf_lo(u.y); acc[3] = dd * bf_hi(u.y);
        acc[4] = dd * bf_lo(u.z); acc[5] = dd * bf_hi(u.z);
        acc[6] = dd * bf_lo(u.w); acc[7] = dd * bf_hi(u.w);
        qgather(m4, csr, dinv, rowstart[node], rowstart[node + 1], t, acc);
        float4 b0 = *(const float4*)&bias[t * 8];
        float4 b1 = *(const float4*)&bias[t * 8 + 4];
        float4 r0, r1;
        r0.x = fmaxf(fmaf(dd, acc[0], b0.x), 0.f);
        r0.y = fmaxf(fmaf(dd, acc[1], b0.y), 0.f);
        r0.z = fmaxf(fmaf(dd, acc[2], b0.z), 0.f);
        r0.w = fmaxf(fmaf(dd, acc[3], b0.w), 0.f);
        r1.x = fmaxf(fmaf(dd, acc[4], b1.x), 0.f);
        r1.y = fmaxf(fmaf(dd, acc[5], b1.y), 0.f);
        r1.z = fmaxf(fmaf(dd, acc[6], b1.z), 0.f);
        r1.w = fmaxf(fmaf(dd, acc[7], b1.w), 0.f);
        *(float4*)&smx[nl][t * 8] = r0;
        *(float4*)&smx[nl][t * 8 + 4] = r1;
    }
    if (t == 0) sgid[nl] = valid ? batch[node] : -1;
    __syncthreads();
    if (threadIdx.x < HDIM) {
        int c = threadIdx.x;
        int curg = -1;
        float run = 0.f;
#pragma unroll
        for (int r = 0; r < 16; ++r) {
            int gg = sgid[r];
            if (gg < 0) continue;
            if (gg != curg) {
                if (curg >= 0) atomicMax(&g[curg * HDIM + c], __float_as_uint(run));
                curg = gg;
                run = smx[r][c];
            } else {
                run = fmaxf(run, smx[r][c]);
            }
        }
        if (curg >= 0) atomicMax(&g[curg * HDIM + c], __float_as_uint(run));
    }
}

// ---------------- MLP head + log_softmax ----------------
__global__ __launch_bounds__(128) void mlp_kernel(const unsigned int* __restrict__ gbits,
                                                  const float* __restrict__ W3,
                                                  const float* __restrict__ b3,
                                                  const float* __restrict__ W4,
                                                  const float* __restrict__ b4,
                                                  float* __restrict__ out) {
    __shared__ float gs[HDIM];
    __shared__ float r0[HDIM];
    __shared__ float r1[HDIM];
    int j = threadIdx.x;
    int b = blockIdx.x;
    gs[j] = __uint_as_float(gbits[b * HDIM + j]);
    __syncthreads();
    float acc = b3[j];
#pragma unroll 8
    for (int k = 0; k < HDIM; ++k) acc = fmaf(gs[k], W3[k * HDIM + j], acc);
    float z = fmaxf(acc, 0.f);
    r0[j] = z * W4[j * 2 + 0];
    r1[j] = z * W4[j * 2 + 1];
    __syncthreads();
    for (int off = 64; off > 0; off >>= 1) {
        if (j < off) {
            r0[j] += r0[j + off];
            r1[j] += r1[j + off];
        }
        __syncthreads();
    }
    if (j == 0) {
        float l0 = r0[0] + b4[0];
        float l1 = r1[0] + b4[1];
        float mx = fmaxf(l0, l1);
        float lse = mx + logf(expf(l0 - mx) + expf(l1 - mx));
        out[b * 2 + 0] = l0 - lse;
        out[b * 2 + 1] = l1 - lse;
    }
}

extern "C" void kernel_launch(void* const* d_in, const int* in_sizes, int n_in,
                              void* d_out, int out_size, void* d_ws, size_t ws_size,
                              hipStream_t stream) {
    const float* x  = (const float*)d_in[0];
    const float* W1 = (const float*)d_in[1];
    const float* b1 = (const float*)d_in[2];
    const float* W2 = (const float*)d_in[3];
    const float* b2 = (const float*)d_in[4];
    const float* W3 = (const float*)d_in[5];
    const float* b3 = (const float*)d_in[6];
    const float* W4 = (const float*)d_in[7];
    const float* b4 = (const float*)d_in[8];
    const int* ei    = (const int*)d_in[9];
    const int* batch = (const int*)d_in[10];

    const int N = in_sizes[0] / HDIM;   // 50000
    const int E = in_sizes[9] / 2;      // 640000
    const int G = out_size / 2;         // 64
    const int* src = ei;
    const int* dst = ei + E;

    // ---- workspace layout (16B-aligned blocks) ----
    const int Nr = ((N + 63) / 64) * 64;
    char* wsb = (char*)d_ws;
    size_t o = 0;
    int* cnt = (int*)(wsb + o);            o += (size_t)Nr * 4;
    unsigned int* g = (unsigned int*)(wsb + o); o += (size_t)G * HDIM * 4;
    size_t zero_bytes = o;                 // cnt + g zeroed together
    int* cursor = (int*)(wsb + o);         o += (size_t)Nr * 4;   // init by scan3
    int* sums = (int*)(wsb + o);           o += 256 * 4;
    int* rowstart = (int*)(wsb + o);       o += (size_t)(Nr + 64) * 4;
    float* dinv = (float*)(wsb + o);       o += (size_t)Nr * 4;
    int* csr = (int*)(wsb + o);            o += (size_t)E * 4;
    unsigned short* wf1h = (unsigned short*)(wsb + o); o += (size_t)HDIM * HDIM * 2;
    unsigned short* wf1l = (unsigned short*)(wsb + o); o += (size_t)HDIM * HDIM * 2;
    unsigned short* wf2h = (unsigned short*)(wsb + o); o += (size_t)HDIM * HDIM * 2;
    unsigned short* wf2l = (unsigned short*)(wsb + o); o += (size_t)HDIM * HDIM * 2;
    unsigned short* m = (unsigned short*)(wsb + o);    o += (size_t)Nr * HDIM * 2;
    unsigned short* h = (unsigned short*)(wsb + o);    o += (size_t)Nr * HDIM * 2;
    (void)ws_size; (void)n_in;

    hipMemsetAsync(d_ws, 0, zero_bytes, stream);

    int eblocks = (E + 255) / 256;
    int nb = (N + SCAN_B - 1) / SCAN_B;

    count_kernel<<<eblocks, 256, 0, stream>>>(dst, cnt, E);
    scan1_kernel<<<nb, SCAN_B, 0, stream>>>(cnt, rowstart, sums, dinv, N);
    scan2_kernel<<<1, SCAN_B, 0, stream>>>(sums, nb);
    scan3_kernel<<<nb, SCAN_B, 0, stream>>>(cnt, rowstart, sums, cursor, N, E);
    fill_kernel<<<eblocks, 256, 0, stream>>>(src, dst, cursor, csr, E);

    wfrag_kernel<<<128, 256, 0, stream>>>(W1, W2, wf1h, wf1l, wf2h, wf2l);

    int gemm_blocks = (N + GBM - 1) / GBM;
    int agg_blocks = (N + 15) / 16;

    // layer 1: m = bf16(x@W1); h = bf16(relu(dinv.*agg(m)+b1))
    gemm_f32_kernel<<<gemm_blocks, 256, 0, stream>>>(x, wf1h, wf1l, m, N);
    agg_kernel<<<agg_blocks, 256, 0, stream>>>((const uint4*)m, rowstart, csr,
                                               dinv, b1, (uint4*)h, N);
    // layer 2: m = bf16(h@W2); g = segmax(relu(dinv.*agg(m)+b2))  [pool fused]
    gemm_bf16_kernel<<<gemm_blocks, 256, 0, stream>>>(h, wf2h, wf2l, m, N);
    agg_pool_kernel<<<agg_blocks, 256, 0, stream>>>((const uint4*)m, rowstart, csr,
                                                    dinv, b2, batch, g, N);

    // MLP head + log_softmax
    mlp_kernel<<<G, 128, 0, stream>>>(g, W3, b3, W4, b4, (float*)d_out);
}

// Round 7
// 247.164 us; speedup vs baseline: 1.6617x; 1.0302x over previous
//
#include <hip/hip_runtime.h>
#include <hip/hip_bf16.h>
#include <math.h>

// ---------------- constants ----------------
#define HDIM 128
#define SCAN_B 256

typedef short bfrag __attribute__((ext_vector_type(8)));   // 8 bf16 (4 VGPRs)
typedef float f32x4 __attribute__((ext_vector_type(4)));   // 4 fp32 acc

__device__ inline unsigned short f2bf_rne(float x) {
    unsigned u = __float_as_uint(x);
    u = (u + 0x7fffu + ((u >> 16) & 1u)) >> 16;
    return (unsigned short)u;
}
__device__ inline float bf_lo(unsigned u) { return __uint_as_float(u << 16); }
__device__ inline float bf_hi(unsigned u) { return __uint_as_float(u & 0xffff0000u); }
__device__ inline unsigned bf_pack(float lo, float hi) {
    return ((unsigned)f2bf_rne(hi) << 16) | (unsigned)f2bf_rne(lo);
}

// ---------------- device bodies ----------------

__device__ inline void count_body(int b, const int* __restrict__ dst,
                                  int* __restrict__ cnt, int E) {
    int e = b * 256 + threadIdx.x;
    if (e < E) atomicAdd(&cnt[dst[e]], 1);
}

// W -> fragment-ordered bf16 hi/lo, column-permuted: physical slot (nt, lm)
// carries logical column n_l = lm*8 + nt (so epilogue stores are 16B packed).
__device__ inline void wfrag_body(int b, const float* __restrict__ W1,
                                  const float* __restrict__ W2,
                                  unsigned short* __restrict__ w1h,
                                  unsigned short* __restrict__ w1l,
                                  unsigned short* __restrict__ w2h,
                                  unsigned short* __restrict__ w2l) {
    const float* W = (b < 64) ? W1 : W2;
    unsigned short* whi = (b < 64) ? w1h : w2h;
    unsigned short* wlo = (b < 64) ? w1l : w2l;
    int idx = (b & 63) * 256 + threadIdx.x;     // 0..16383
    int k = idx >> 7;
    int n = idx & 127;
    int kt = k >> 5, q = (k >> 3) & 3, j = k & 7;
    int lm = n >> 3, nt = n & 7;
    int lane = q * 16 + lm;
    int o = ((kt * 8 + nt) * 64 + lane) * 8 + j;
    float x = W[idx];
    unsigned short hb = f2bf_rne(x);
    float hf = __uint_as_float(((unsigned)hb) << 16);
    unsigned short lb = f2bf_rne(x - hf);
    whi[o] = hb;
    wlo[o] = lb;
}

__device__ inline void fill_body(int b, const int* __restrict__ srcv,
                                 const int* __restrict__ dstv,
                                 int* __restrict__ cursor,
                                 int* __restrict__ csr, int E) {
    int e = b * 256 + threadIdx.x;
    if (e < E) {
        int d = dstv[e];
        int pos = atomicAdd(&cursor[d], 1);
        csr[pos] = srcv[e];
    }
}

// MFMA GEMM (fp32 A), 64-row tiles, split 3-MFMA: C ~= Ah*Wh + Al*Wh + Ah*Wl
#define GBM 64
__device__ inline void gemm_f32_body(int b, const float* __restrict__ A,
                                     const unsigned short* __restrict__ whi,
                                     const unsigned short* __restrict__ wlo,
                                     unsigned short* __restrict__ C, int Nrows) {
    int tid = threadIdx.x;
    int w = tid >> 6, L = tid & 63;
    int lm = L & 15, lq = L >> 4;
    int row0 = b * GBM + w * 16;

    f32x4 acc[8];
#pragma unroll
    for (int nt = 0; nt < 8; ++nt) acc[nt] = (f32x4)(0.f);

#pragma unroll
    for (int kt = 0; kt < 4; ++kt) {
        int gr = row0 + lm;
        float4 v0 = make_float4(0.f, 0.f, 0.f, 0.f);
        float4 v1 = v0;
        if (gr < Nrows) {
            const float* p = &A[(size_t)gr * HDIM + kt * 32 + lq * 8];
            v0 = *(const float4*)p;
            v1 = *(const float4*)(p + 4);
        }
        float xv[8] = {v0.x, v0.y, v0.z, v0.w, v1.x, v1.y, v1.z, v1.w};
        bfrag ah, al;
#pragma unroll
        for (int j = 0; j < 8; ++j) {
            float x = xv[j];
            unsigned short hb = f2bf_rne(x);
            float hf = __uint_as_float(((unsigned)hb) << 16);
            unsigned short lb = f2bf_rne(x - hf);
            ah[j] = (short)hb;
            al[j] = (short)lb;
        }
#pragma unroll
        for (int nt = 0; nt < 8; ++nt) {
            int o = ((kt * 8 + nt) * 64 + L) * 8;
            bfrag wh = *(const bfrag*)&whi[o];
            bfrag wl = *(const bfrag*)&wlo[o];
            acc[nt] = __builtin_amdgcn_mfma_f32_16x16x32_bf16(ah, wh, acc[nt], 0, 0, 0);
            acc[nt] = __builtin_amdgcn_mfma_f32_16x16x32_bf16(al, wh, acc[nt], 0, 0, 0);
            acc[nt] = __builtin_amdgcn_mfma_f32_16x16x32_bf16(ah, wl, acc[nt], 0, 0, 0);
        }
    }

#pragma unroll
    for (int i = 0; i < 4; ++i) {
        int gr = row0 + lq * 4 + i;
        if (gr < Nrows) {
            bfrag e;
#pragma unroll
            for (int nt = 0; nt < 8; ++nt) e[nt] = (short)f2bf_rne(acc[nt][i]);
            *(bfrag*)&C[(size_t)gr * HDIM + lm * 8] = e;
        }
    }
}

// ---------------- megakernel 1: count || wfrag ----------------
__global__ __launch_bounds__(256) void mega1_kernel(const int* __restrict__ dst,
                                                    int* __restrict__ cnt, int E,
                                                    int count_blocks,
                                                    const float* __restrict__ W1,
                                                    const float* __restrict__ W2,
                                                    unsigned short* __restrict__ w1h,
                                                    unsigned short* __restrict__ w1l,
                                                    unsigned short* __restrict__ w2h,
                                                    unsigned short* __restrict__ w2l) {
    int b = blockIdx.x;
    if (b < count_blocks) count_body(b, dst, cnt, E);
    else wfrag_body(b - count_blocks, W1, W2, w1h, w1l, w2h, w2l);
}

// ---------------- megakernel 3: fill || gemm_f32(layer1) ----------------
__global__ __launch_bounds__(256) void mega3_kernel(const int* __restrict__ srcv,
                                                    const int* __restrict__ dstv,
                                                    int* __restrict__ cursor,
                                                    int* __restrict__ csr, int E,
                                                    int fill_blocks,
                                                    const float* __restrict__ A,
                                                    const unsigned short* __restrict__ whi,
                                                    const unsigned short* __restrict__ wlo,
                                                    unsigned short* __restrict__ C, int Nrows) {
    int b = blockIdx.x;
    if (b < fill_blocks) fill_body(b, srcv, dstv, cursor, csr, E);
    else gemm_f32_body(b - fill_blocks, A, whi, wlo, C, Nrows);
}

// ---------------- scan kernels ----------------
__global__ __launch_bounds__(SCAN_B) void scan1_kernel(const int* __restrict__ cnt,
                                                       int* __restrict__ rowstart,
                                                       int* __restrict__ sums,
                                                       float* __restrict__ dinv, int n) {
    __shared__ int s[SCAN_B];
    int t = threadIdx.x;
    int idx = blockIdx.x * SCAN_B + t;
    int v = (idx < n) ? cnt[idx] : 0;
    if (idx < n) dinv[idx] = rsqrtf((float)(v + 1));   // +1 self-loop
    s[t] = v;
    __syncthreads();
    for (int off = 1; off < SCAN_B; off <<= 1) {
        int x = (t >= off) ? s[t - off] : 0;
        __syncthreads();
        s[t] += x;
        __syncthreads();
    }
    if (idx < n) rowstart[idx] = s[t];
    if (t == SCAN_B - 1) sums[blockIdx.x] = s[t];
}

__global__ __launch_bounds__(SCAN_B) void scan2_kernel(int* __restrict__ sums, int nb) {
    __shared__ int s[SCAN_B];
    int t = threadIdx.x;
    int v = (t < nb) ? sums[t] : 0;
    s[t] = v;
    __syncthreads();
    for (int off = 1; off < SCAN_B; off <<= 1) {
        int x = (t >= off) ? s[t - off] : 0;
        __syncthreads();
        s[t] += x;
        __syncthreads();
    }
    if (t < nb) sums[t] = s[t] - v;
}

__global__ __launch_bounds__(SCAN_B) void scan3_kernel(const int* __restrict__ cnt,
                                                       int* __restrict__ rowstart,
                                                       const int* __restrict__ sums,
                                                       int* __restrict__ cursor,
                                                       int n, int E) {
    int idx = blockIdx.x * SCAN_B + threadIdx.x;
    if (idx < n) {
        int incl = rowstart[idx];
        int excl = incl - cnt[idx] + sums[blockIdx.x];
        rowstart[idx] = excl;
        cursor[idx] = excl;
    }
    if (idx == 0) rowstart[n] = E;
}

// ---------------- MFMA GEMM (bf16 A): 2 MFMAs per tile ----------------
__global__ __launch_bounds__(256) void gemm_bf16_kernel(
        const unsigned short* __restrict__ A16,
        const unsigned short* __restrict__ whi,
        const unsigned short* __restrict__ wlo,
        unsigned short* __restrict__ C, int Nrows) {
    int tid = threadIdx.x;
    int w = tid >> 6, L = tid & 63;
    int lm = L & 15, lq = L >> 4;
    int row0 = blockIdx.x * GBM + w * 16;

    f32x4 acc[8];
#pragma unroll
    for (int nt = 0; nt < 8; ++nt) acc[nt] = (f32x4)(0.f);

#pragma unroll
    for (int kt = 0; kt < 4; ++kt) {
        int gr = row0 + lm;
        bfrag ah = (bfrag)(short)0;
        if (gr < Nrows) ah = *(const bfrag*)&A16[(size_t)gr * HDIM + kt * 32 + lq * 8];
#pragma unroll
        for (int nt = 0; nt < 8; ++nt) {
            int o = ((kt * 8 + nt) * 64 + L) * 8;
            bfrag wh = *(const bfrag*)&whi[o];
            bfrag wl = *(const bfrag*)&wlo[o];
            acc[nt] = __builtin_amdgcn_mfma_f32_16x16x32_bf16(ah, wh, acc[nt], 0, 0, 0);
            acc[nt] = __builtin_amdgcn_mfma_f32_16x16x32_bf16(ah, wl, acc[nt], 0, 0, 0);
        }
    }

#pragma unroll
    for (int i = 0; i < 4; ++i) {
        int gr = row0 + lq * 4 + i;
        if (gr < Nrows) {
            bfrag e;
#pragma unroll
            for (int nt = 0; nt < 8; ++nt) e[nt] = (short)f2bf_rne(acc[nt][i]);
            *(bfrag*)&C[(size_t)gr * HDIM + lm * 8] = e;
        }
    }
}

// ---------------- quarter-wave gather, 4-deep software pipeline ----------------
// 16 lanes x uint4 per node row; 4 independent gathers in flight per chain.
// NOTE: macro params must NOT collide with vector member names (.x/.y/.z/.w).
#define QACC(UV, WT)                                   \
    acc[0] = fmaf(WT, bf_lo((UV).x), acc[0]);          \
    acc[1] = fmaf(WT, bf_hi((UV).x), acc[1]);          \
    acc[2] = fmaf(WT, bf_lo((UV).y), acc[2]);          \
    acc[3] = fmaf(WT, bf_hi((UV).y), acc[3]);          \
    acc[4] = fmaf(WT, bf_lo((UV).z), acc[4]);          \
    acc[5] = fmaf(WT, bf_hi((UV).z), acc[5]);          \
    acc[6] = fmaf(WT, bf_lo((UV).w), acc[6]);          \
    acc[7] = fmaf(WT, bf_hi((UV).w), acc[7]);

__device__ inline void qgather(const uint4* __restrict__ m4,
                               const int* __restrict__ csr,
                               const float* __restrict__ dinv,
                               int p, int pend, int t, float* acc) {
    for (; p + 4 <= pend; p += 4) {
        int s0 = csr[p], s1 = csr[p + 1], s2 = csr[p + 2], s3 = csr[p + 3];
        float w0 = dinv[s0], w1 = dinv[s1], w2 = dinv[s2], w3 = dinv[s3];
        uint4 u0 = m4[(size_t)s0 * 16 + t];
        uint4 u1 = m4[(size_t)s1 * 16 + t];
        uint4 u2 = m4[(size_t)s2 * 16 + t];
        uint4 u3 = m4[(size_t)s3 * 16 + t];
        QACC(u0, w0); QACC(u1, w1); QACC(u2, w2); QACC(u3, w3);
    }
    if (p + 2 <= pend) {
        int s0 = csr[p], s1 = csr[p + 1];
        float w0 = dinv[s0], w1 = dinv[s1];
        uint4 u0 = m4[(size_t)s0 * 16 + t];
        uint4 u1 = m4[(size_t)s1 * 16 + t];
        QACC(u0, w0); QACC(u1, w1);
        p += 2;
    }
    if (p < pend) {
        int s0 = csr[p];
        float w0 = dinv[s0];
        uint4 u0 = m4[(size_t)s0 * 16 + t];
        QACC(u0, w0);
    }
}

// ---------------- agg layer 1: 16 nodes/block, bf16-packed output ----------------
__global__ __launch_bounds__(256) void agg_kernel(const uint4* __restrict__ m4,
                                                  const int* __restrict__ rowstart,
                                                  const int* __restrict__ csr,
                                                  const float* __restrict__ dinv,
                                                  const float* __restrict__ bias,
                                                  uint4* __restrict__ out, int n) {
    int t = threadIdx.x & 15;
    int node = blockIdx.x * 16 + (threadIdx.x >> 4);
    if (node >= n) return;
    float dd = dinv[node];
    float acc[8];
    {   // self term (dinv[dst] factored out of the edge sum)
        uint4 u = m4[(size_t)node * 16 + t];
        acc[0] = dd * bf_lo(u.x); acc[1] = dd * bf_hi(u.x);
        acc[2] = dd * bf_lo(u.y); acc[3] = dd * bf_hi(u.y);
        acc[4] = dd * bf_lo(u.z); acc[5] = dd * bf_hi(u.z);
        acc[6] = dd * bf_lo(u.w); acc[7] = dd * bf_hi(u.w);
    }
    qgather(m4, csr, dinv, rowstart[node], rowstart[node + 1], t, acc);
    float4 b0 = *(const float4*)&bias[t * 8];
    float4 b1 = *(const float4*)&bias[t * 8 + 4];
    uint4 o;
    o.x = bf_pack(fmaxf(fmaf(dd, acc[0], b0.x), 0.f), fmaxf(fmaf(dd, acc[1], b0.y), 0.f));
    o.y = bf_pack(fmaxf(fmaf(dd, acc[2], b0.z), 0.f), fmaxf(fmaf(dd, acc[3], b0.w), 0.f));
    o.z = bf_pack(fmaxf(fmaf(dd, acc[4], b1.x), 0.f), fmaxf(fmaf(dd, acc[5], b1.y), 0.f));
    o.w = bf_pack(fmaxf(fmaf(dd, acc[6], b1.z), 0.f), fmaxf(fmaf(dd, acc[7], b1.w), 0.f));
    out[(size_t)node * 16 + t] = o;
}

// ---------------- agg layer 2 fused with global max pool ----------------
__global__ __launch_bounds__(256) void agg_pool_kernel(const uint4* __restrict__ m4,
                                                       const int* __restrict__ rowstart,
                                                       const int* __restrict__ csr,
                                                       const float* __restrict__ dinv,
                                                       const float* __restrict__ bias,
                                                       const int* __restrict__ batch,
                                                       unsigned int* __restrict__ g, int n) {
    __shared__ float smx[16][HDIM];
    __shared__ int sgid[16];
    int t = threadIdx.x & 15;
    int nl = threadIdx.x >> 4;              // node-in-block 0..15
    int node = blockIdx.x * 16 + nl;
    bool valid = node < n;
    if (valid) {
        float dd = dinv[node];
        float acc[8];
        uint4 u = m4[(size_t)node * 16 + t];
        acc[0] = dd * bf_lo(u.x); acc[1] = dd * bf_hi(u.x);
        acc[2] = dd * bf_lo(u.y); acc[3] = dd * bf_hi(u.y);
        acc[4] = dd * bf_lo(u.z); acc[5] = dd * bf_hi(u.z);
        acc[6] = dd * bf_lo(u.w); acc[7] = dd * bf_hi(u.w);
        qgather(m4, csr, dinv, rowstart[node], rowstart[node + 1], t, acc);
        float4 b0 = *(const float4*)&bias[t * 8];
        float4 b1 = *(const float4*)&bias[t * 8 + 4];
        float4 r0, r1;
        r0.x = fmaxf(fmaf(dd, acc[0], b0.x), 0.f);
        r0.y = fmaxf(fmaf(dd, acc[1], b0.y), 0.f);
        r0.z = fmaxf(fmaf(dd, acc[2], b0.z), 0.f);
        r0.w = fmaxf(fmaf(dd, acc[3], b0.w), 0.f);
        r1.x = fmaxf(fmaf(dd, acc[4], b1.x), 0.f);
        r1.y = fmaxf(fmaf(dd, acc[5], b1.y), 0.f);
        r1.z = fmaxf(fmaf(dd, acc[6], b1.z), 0.f);
        r1.w = fmaxf(fmaf(dd, acc[7], b1.w), 0.f);
        *(float4*)&smx[nl][t * 8] = r0;
        *(float4*)&smx[nl][t * 8 + 4] = r1;
    }
    if (t == 0) sgid[nl] = valid ? batch[node] : -1;
    __syncthreads();
    if (threadIdx.x < HDIM) {
        int c = threadIdx.x;
        int curg = -1;
        float run = 0.f;
#pragma unroll
        for (int r = 0; r < 16; ++r) {
            int gg = sgid[r];
            if (gg < 0) continue;
            if (gg != curg) {
                if (curg >= 0) atomicMax(&g[curg * HDIM + c], __float_as_uint(run));
                curg = gg;
                run = smx[r][c];
            } else {
                run = fmaxf(run, smx[r][c]);
            }
        }
        if (curg >= 0) atomicMax(&g[curg * HDIM + c], __float_as_uint(run));
    }
}

// ---------------- MLP head + log_softmax ----------------
__global__ __launch_bounds__(128) void mlp_kernel(const unsigned int* __restrict__ gbits,
                                                  const float* __restrict__ W3,
                                                  const float* __restrict__ b3,
                                                  const float* __restrict__ W4,
                                                  const float* __restrict__ b4,
                                                  float* __restrict__ out) {
    __shared__ float gs[HDIM];
    __shared__ float r0[HDIM];
    __shared__ float r1[HDIM];
    int j = threadIdx.x;
    int b = blockIdx.x;
    gs[j] = __uint_as_float(gbits[b * HDIM + j]);
    __syncthreads();
    float acc = b3[j];
#pragma unroll 8
    for (int k = 0; k < HDIM; ++k) acc = fmaf(gs[k], W3[k * HDIM + j], acc);
    float z = fmaxf(acc, 0.f);
    r0[j] = z * W4[j * 2 + 0];
    r1[j] = z * W4[j * 2 + 1];
    __syncthreads();
    for (int off = 64; off > 0; off >>= 1) {
        if (j < off) {
            r0[j] += r0[j + off];
            r1[j] += r1[j + off];
        }
        __syncthreads();
    }
    if (j == 0) {
        float l0 = r0[0] + b4[0];
        float l1 = r1[0] + b4[1];
        float mx = fmaxf(l0, l1);
        float lse = mx + logf(expf(l0 - mx) + expf(l1 - mx));
        out[b * 2 + 0] = l0 - lse;
        out[b * 2 + 1] = l1 - lse;
    }
}

extern "C" void kernel_launch(void* const* d_in, const int* in_sizes, int n_in,
                              void* d_out, int out_size, void* d_ws, size_t ws_size,
                              hipStream_t stream) {
    const float* x  = (const float*)d_in[0];
    const float* W1 = (const float*)d_in[1];
    const float* b1 = (const float*)d_in[2];
    const float* W2 = (const float*)d_in[3];
    const float* b2 = (const float*)d_in[4];
    const float* W3 = (const float*)d_in[5];
    const float* b3 = (const float*)d_in[6];
    const float* W4 = (const float*)d_in[7];
    const float* b4 = (const float*)d_in[8];
    const int* ei    = (const int*)d_in[9];
    const int* batch = (const int*)d_in[10];

    const int N = in_sizes[0] / HDIM;   // 50000
    const int E = in_sizes[9] / 2;      // 640000
    const int G = out_size / 2;         // 64
    const int* src = ei;
    const int* dst = ei + E;

    // ---- workspace layout (16B-aligned blocks) ----
    const int Nr = ((N + 63) / 64) * 64;
    char* wsb = (char*)d_ws;
    size_t o = 0;
    int* cnt = (int*)(wsb + o);            o += (size_t)Nr * 4;
    unsigned int* g = (unsigned int*)(wsb + o); o += (size_t)G * HDIM * 4;
    size_t zero_bytes = o;                 // cnt + g zeroed together
    int* cursor = (int*)(wsb + o);         o += (size_t)Nr * 4;   // init by scan3
    int* sums = (int*)(wsb + o);           o += 256 * 4;
    int* rowstart = (int*)(wsb + o);       o += (size_t)(Nr + 64) * 4;
    float* dinv = (float*)(wsb + o);       o += (size_t)Nr * 4;
    int* csr = (int*)(wsb + o);            o += (size_t)E * 4;
    unsigned short* wf1h = (unsigned short*)(wsb + o); o += (size_t)HDIM * HDIM * 2;
    unsigned short* wf1l = (unsigned short*)(wsb + o); o += (size_t)HDIM * HDIM * 2;
    unsigned short* wf2h = (unsigned short*)(wsb + o); o += (size_t)HDIM * HDIM * 2;
    unsigned short* wf2l = (unsigned short*)(wsb + o); o += (size_t)HDIM * HDIM * 2;
    unsigned short* m = (unsigned short*)(wsb + o);    o += (size_t)Nr * HDIM * 2;
    unsigned short* h = (unsigned short*)(wsb + o);    o += (size_t)Nr * HDIM * 2;
    (void)ws_size; (void)n_in;

    (void)hipMemsetAsync(d_ws, 0, zero_bytes, stream);

    int eblocks = (E + 255) / 256;          // 2500
    int nb = (N + SCAN_B - 1) / SCAN_B;     // 196
    int gemm_blocks = (N + GBM - 1) / GBM;  // 782
    int agg_blocks = (N + 15) / 16;

    // K1: count || wfrag  (independent)
    mega1_kernel<<<eblocks + 128, 256, 0, stream>>>(dst, cnt, E, eblocks,
                                                    W1, W2, wf1h, wf1l, wf2h, wf2l);
    // K2: scan chain
    scan1_kernel<<<nb, SCAN_B, 0, stream>>>(cnt, rowstart, sums, dinv, N);
    scan2_kernel<<<1, SCAN_B, 0, stream>>>(sums, nb);
    scan3_kernel<<<nb, SCAN_B, 0, stream>>>(cnt, rowstart, sums, cursor, N, E);
    // K3: fill || gemm layer 1 (gemm depends only on x + wfrag)
    mega3_kernel<<<eblocks + gemm_blocks, 256, 0, stream>>>(src, dst, cursor, csr, E,
                                                            eblocks, x, wf1h, wf1l, m, N);
    // layer 1 aggregate
    agg_kernel<<<agg_blocks, 256, 0, stream>>>((const uint4*)m, rowstart, csr,
                                               dinv, b1, (uint4*)h, N);
    // layer 2: m = bf16(h@W2); g = segmax(relu(dinv.*agg(m)+b2))  [pool fused]
    gemm_bf16_kernel<<<gemm_blocks, 256, 0, stream>>>(h, wf2h, wf2l, m, N);
    agg_pool_kernel<<<agg_blocks, 256, 0, stream>>>((const uint4*)m, rowstart, csr,
                                                    dinv, b2, batch, g, N);
    // MLP head + log_softmax
    mlp_kernel<<<G, 128, 0, stream>>>(g, W3, b3, W4, b4, (float*)d_out);
}

// Round 8
// 205.738 us; speedup vs baseline: 1.9963x; 1.2014x over previous
//
#include <hip/hip_runtime.h>
#include <hip/hip_bf16.h>
#include <math.h>

// ---------------- constants ----------------
#define HDIM 128
#define SCAN_B 256
#define NBLK 256          // edge blocks for hist/scatter passes

typedef short bfrag __attribute__((ext_vector_type(8)));   // 8 bf16 (4 VGPRs)
typedef float f32x4 __attribute__((ext_vector_type(4)));   // 4 fp32 acc

__device__ inline unsigned short f2bf_rne(float x) {
    unsigned u = __float_as_uint(x);
    u = (u + 0x7fffu + ((u >> 16) & 1u)) >> 16;
    return (unsigned short)u;
}
__device__ inline float bf_lo(unsigned u) { return __uint_as_float(u << 16); }
__device__ inline float bf_hi(unsigned u) { return __uint_as_float(u & 0xffff0000u); }
__device__ inline unsigned bf_pack(float lo, float hi) {
    return ((unsigned)f2bf_rne(hi) << 16) | (unsigned)f2bf_rne(lo);
}

// ---------------- device bodies ----------------

// Pass A: per-block LDS histogram over coarse buckets (dst>>8); no global atomics.
__device__ inline void hist_body(int b, const int* __restrict__ dst,
                                 int* __restrict__ hist, int E, int chunk, int nbuck) {
    __shared__ int hl[256];
    int t = threadIdx.x;
    hl[t] = 0;
    __syncthreads();
    int start = b * chunk, end = min(E, start + chunk);
    for (int e = start + t; e < end; e += 256) atomicAdd(&hl[dst[e] >> 8], 1);
    __syncthreads();
    if (t < nbuck) hist[t * NBLK + b] = hl[t];
}

// W -> fragment-ordered bf16 hi/lo, column-permuted: physical slot (nt, lm)
// carries logical column n_l = lm*8 + nt (so epilogue stores are 16B packed).
__device__ inline void wfrag_body(int b, const float* __restrict__ W1,
                                  const float* __restrict__ W2,
                                  unsigned short* __restrict__ w1h,
                                  unsigned short* __restrict__ w1l,
                                  unsigned short* __restrict__ w2h,
                                  unsigned short* __restrict__ w2l) {
    const float* W = (b < 64) ? W1 : W2;
    unsigned short* whi = (b < 64) ? w1h : w2h;
    unsigned short* wlo = (b < 64) ? w1l : w2l;
    int idx = (b & 63) * 256 + threadIdx.x;     // 0..16383
    int k = idx >> 7;
    int n = idx & 127;
    int kt = k >> 5, q = (k >> 3) & 3, j = k & 7;
    int lm = n >> 3, nt = n & 7;
    int lane = q * 16 + lm;
    int o = ((kt * 8 + nt) * 64 + lane) * 8 + j;
    float x = W[idx];
    unsigned short hb = f2bf_rne(x);
    float hf = __uint_as_float(((unsigned)hb) << 16);
    unsigned short lb = f2bf_rne(x - hf);
    whi[o] = hb;
    wlo[o] = lb;
}

// Pass C: scatter edges into bucket-sorted order via LDS cursors (no global atomics).
__device__ inline void scatter_body(int b, const int* __restrict__ srcv,
                                    const int* __restrict__ dstv,
                                    const int* __restrict__ hscan,
                                    int2* __restrict__ sorted,
                                    int E, int chunk, int nbuck) {
    __shared__ int cur[256];
    int t = threadIdx.x;
    if (t < nbuck) cur[t] = hscan[t * NBLK + b];
    __syncthreads();
    int start = b * chunk, end = min(E, start + chunk);
    for (int e = start + t; e < end; e += 256) {
        int d = dstv[e];
        int pos = atomicAdd(&cur[d >> 8], 1);
        sorted[pos] = make_int2(srcv[e], d);
    }
}

// MFMA GEMM (fp32 A), 64-row tiles, split 3-MFMA: C ~= Ah*Wh + Al*Wh + Ah*Wl
#define GBM 64
__device__ inline void gemm_f32_body(int b, const float* __restrict__ A,
                                     const unsigned short* __restrict__ whi,
                                     const unsigned short* __restrict__ wlo,
                                     unsigned short* __restrict__ C, int Nrows) {
    int tid = threadIdx.x;
    int w = tid >> 6, L = tid & 63;
    int lm = L & 15, lq = L >> 4;
    int row0 = b * GBM + w * 16;

    f32x4 acc[8];
#pragma unroll
    for (int nt = 0; nt < 8; ++nt) acc[nt] = (f32x4)(0.f);

#pragma unroll
    for (int kt = 0; kt < 4; ++kt) {
        int gr = row0 + lm;
        float4 v0 = make_float4(0.f, 0.f, 0.f, 0.f);
        float4 v1 = v0;
        if (gr < Nrows) {
            const float* p = &A[(size_t)gr * HDIM + kt * 32 + lq * 8];
            v0 = *(const float4*)p;
            v1 = *(const float4*)(p + 4);
        }
        float xv[8] = {v0.x, v0.y, v0.z, v0.w, v1.x, v1.y, v1.z, v1.w};
        bfrag ah, al;
#pragma unroll
        for (int j = 0; j < 8; ++j) {
            float x = xv[j];
            unsigned short hb = f2bf_rne(x);
            float hf = __uint_as_float(((unsigned)hb) << 16);
            unsigned short lb = f2bf_rne(x - hf);
            ah[j] = (short)hb;
            al[j] = (short)lb;
        }
#pragma unroll
        for (int nt = 0; nt < 8; ++nt) {
            int o = ((kt * 8 + nt) * 64 + L) * 8;
            bfrag wh = *(const bfrag*)&whi[o];
            bfrag wl = *(const bfrag*)&wlo[o];
            acc[nt] = __builtin_amdgcn_mfma_f32_16x16x32_bf16(ah, wh, acc[nt], 0, 0, 0);
            acc[nt] = __builtin_amdgcn_mfma_f32_16x16x32_bf16(al, wh, acc[nt], 0, 0, 0);
            acc[nt] = __builtin_amdgcn_mfma_f32_16x16x32_bf16(ah, wl, acc[nt], 0, 0, 0);
        }
    }

#pragma unroll
    for (int i = 0; i < 4; ++i) {
        int gr = row0 + lq * 4 + i;
        if (gr < Nrows) {
            bfrag e;
#pragma unroll
            for (int nt = 0; nt < 8; ++nt) e[nt] = (short)f2bf_rne(acc[nt][i]);
            *(bfrag*)&C[(size_t)gr * HDIM + lm * 8] = e;
        }
    }
}

// ---------------- megakernel 1: hist || wfrag ----------------
__global__ __launch_bounds__(256) void mega1_kernel(const int* __restrict__ dst,
                                                    int* __restrict__ hist, int E,
                                                    int chunk, int nbuck,
                                                    const float* __restrict__ W1,
                                                    const float* __restrict__ W2,
                                                    unsigned short* __restrict__ w1h,
                                                    unsigned short* __restrict__ w1l,
                                                    unsigned short* __restrict__ w2h,
                                                    unsigned short* __restrict__ w2l) {
    int b = blockIdx.x;
    if (b < NBLK) hist_body(b, dst, hist, E, chunk, nbuck);
    else wfrag_body(b - NBLK, W1, W2, w1h, w1l, w2h, w2l);
}

// ---------------- megakernel 3: scatter || gemm_f32(layer1) ----------------
__global__ __launch_bounds__(256) void mega3_kernel(const int* __restrict__ srcv,
                                                    const int* __restrict__ dstv,
                                                    const int* __restrict__ hscan,
                                                    int2* __restrict__ sorted,
                                                    int E, int chunk, int nbuck,
                                                    const float* __restrict__ A,
                                                    const unsigned short* __restrict__ whi,
                                                    const unsigned short* __restrict__ wlo,
                                                    unsigned short* __restrict__ C, int Nrows) {
    int b = blockIdx.x;
    if (b < NBLK) scatter_body(b, srcv, dstv, hscan, sorted, E, chunk, nbuck);
    else gemm_f32_body(b - NBLK, A, whi, wlo, C, Nrows);
}

// ---------------- generic 3-phase scan (n <= 256*256) ----------------
__global__ __launch_bounds__(SCAN_B) void scan1_kernel(const int* __restrict__ in,
                                                       int* __restrict__ out,
                                                       int* __restrict__ sums, int n) {
    __shared__ int s[SCAN_B];
    int t = threadIdx.x;
    int idx = blockIdx.x * SCAN_B + t;
    int v = (idx < n) ? in[idx] : 0;
    s[t] = v;
    __syncthreads();
    for (int off = 1; off < SCAN_B; off <<= 1) {
        int x = (t >= off) ? s[t - off] : 0;
        __syncthreads();
        s[t] += x;
        __syncthreads();
    }
    if (idx < n) out[idx] = s[t];
    if (t == SCAN_B - 1) sums[blockIdx.x] = s[t];
}

__global__ __launch_bounds__(SCAN_B) void scan2_kernel(int* __restrict__ sums, int nb) {
    __shared__ int s[SCAN_B];
    int t = threadIdx.x;
    int v = (t < nb) ? sums[t] : 0;
    s[t] = v;
    __syncthreads();
    for (int off = 1; off < SCAN_B; off <<= 1) {
        int x = (t >= off) ? s[t - off] : 0;
        __syncthreads();
        s[t] += x;
        __syncthreads();
    }
    if (t < nb) sums[t] = s[t] - v;
}

// out[idx] = exclusive scan (needs original in[])
__global__ __launch_bounds__(SCAN_B) void scan3_kernel(const int* __restrict__ in,
                                                       int* __restrict__ out,
                                                       const int* __restrict__ sums, int n) {
    int idx = blockIdx.x * SCAN_B + threadIdx.x;
    if (idx < n) out[idx] = out[idx] - in[idx] + sums[blockIdx.x];
}

// ---------------- Pass D: per-bucket CSR build (LDS atomics only) ----------------
__global__ __launch_bounds__(256) void csr_kernel(const int2* __restrict__ sorted,
                                                  const int* __restrict__ hscan,
                                                  int* __restrict__ rowstart,
                                                  float* __restrict__ dinv,
                                                  int* __restrict__ csr,
                                                  int N, int E, int nbuck) {
    __shared__ int cnt[256];
    __shared__ int s[256];
    __shared__ int cur[256];
    int b = blockIdx.x;
    int t = threadIdx.x;
    int start = hscan[b * NBLK];
    int end = (b + 1 < nbuck) ? hscan[(b + 1) * NBLK] : E;
    cnt[t] = 0;
    __syncthreads();
    for (int e = start + t; e < end; e += 256)
        atomicAdd(&cnt[sorted[e].y & 255], 1);
    __syncthreads();
    int v = cnt[t];
    s[t] = v;
    __syncthreads();
    for (int off = 1; off < 256; off <<= 1) {
        int x = (t >= off) ? s[t - off] : 0;
        __syncthreads();
        s[t] += x;
        __syncthreads();
    }
    int excl = s[t] - v;
    int node = b * 256 + t;
    if (node < N) {
        rowstart[node] = start + excl;
        dinv[node] = rsqrtf((float)(v + 1));   // +1 self-loop
    }
    if (b == nbuck - 1 && t == 0) rowstart[N] = E;
    cur[t] = start + excl;
    __syncthreads();
    for (int e = start + t; e < end; e += 256) {
        int2 ed = sorted[e];
        int pos = atomicAdd(&cur[ed.y & 255], 1);
        csr[pos] = ed.x;
    }
}

// ---------------- MFMA GEMM (bf16 A): 2 MFMAs per tile ----------------
__global__ __launch_bounds__(256) void gemm_bf16_kernel(
        const unsigned short* __restrict__ A16,
        const unsigned short* __restrict__ whi,
        const unsigned short* __restrict__ wlo,
        unsigned short* __restrict__ C, int Nrows) {
    int tid = threadIdx.x;
    int w = tid >> 6, L = tid & 63;
    int lm = L & 15, lq = L >> 4;
    int row0 = blockIdx.x * GBM + w * 16;

    f32x4 acc[8];
#pragma unroll
    for (int nt = 0; nt < 8; ++nt) acc[nt] = (f32x4)(0.f);

#pragma unroll
    for (int kt = 0; kt < 4; ++kt) {
        int gr = row0 + lm;
        bfrag ah = (bfrag)(short)0;
        if (gr < Nrows) ah = *(const bfrag*)&A16[(size_t)gr * HDIM + kt * 32 + lq * 8];
#pragma unroll
        for (int nt = 0; nt < 8; ++nt) {
            int o = ((kt * 8 + nt) * 64 + L) * 8;
            bfrag wh = *(const bfrag*)&whi[o];
            bfrag wl = *(const bfrag*)&wlo[o];
            acc[nt] = __builtin_amdgcn_mfma_f32_16x16x32_bf16(ah, wh, acc[nt], 0, 0, 0);
            acc[nt] = __builtin_amdgcn_mfma_f32_16x16x32_bf16(ah, wl, acc[nt], 0, 0, 0);
        }
    }

#pragma unroll
    for (int i = 0; i < 4; ++i) {
        int gr = row0 + lq * 4 + i;
        if (gr < Nrows) {
            bfrag e;
#pragma unroll
            for (int nt = 0; nt < 8; ++nt) e[nt] = (short)f2bf_rne(acc[nt][i]);
            *(bfrag*)&C[(size_t)gr * HDIM + lm * 8] = e;
        }
    }
}

// ---------------- quarter-wave gather, 4-deep software pipeline ----------------
#define QACC(UV, WT)                                   \
    acc[0] = fmaf(WT, bf_lo((UV).x), acc[0]);          \
    acc[1] = fmaf(WT, bf_hi((UV).x), acc[1]);          \
    acc[2] = fmaf(WT, bf_lo((UV).y), acc[2]);          \
    acc[3] = fmaf(WT, bf_hi((UV).y), acc[3]);          \
    acc[4] = fmaf(WT, bf_lo((UV).z), acc[4]);          \
    acc[5] = fmaf(WT, bf_hi((UV).z), acc[5]);          \
    acc[6] = fmaf(WT, bf_lo((UV).w), acc[6]);          \
    acc[7] = fmaf(WT, bf_hi((UV).w), acc[7]);

__device__ inline void qgather(const uint4* __restrict__ m4,
                               const int* __restrict__ csr,
                               const float* __restrict__ dinv,
                               int p, int pend, int t, float* acc) {
    for (; p + 4 <= pend; p += 4) {
        int s0 = csr[p], s1 = csr[p + 1], s2 = csr[p + 2], s3 = csr[p + 3];
        float w0 = dinv[s0], w1 = dinv[s1], w2 = dinv[s2], w3 = dinv[s3];
        uint4 u0 = m4[(size_t)s0 * 16 + t];
        uint4 u1 = m4[(size_t)s1 * 16 + t];
        uint4 u2 = m4[(size_t)s2 * 16 + t];
        uint4 u3 = m4[(size_t)s3 * 16 + t];
        QACC(u0, w0); QACC(u1, w1); QACC(u2, w2); QACC(u3, w3);
    }
    if (p + 2 <= pend) {
        int s0 = csr[p], s1 = csr[p + 1];
        float w0 = dinv[s0], w1 = dinv[s1];
        uint4 u0 = m4[(size_t)s0 * 16 + t];
        uint4 u1 = m4[(size_t)s1 * 16 + t];
        QACC(u0, w0); QACC(u1, w1);
        p += 2;
    }
    if (p < pend) {
        int s0 = csr[p];
        float w0 = dinv[s0];
        uint4 u0 = m4[(size_t)s0 * 16 + t];
        QACC(u0, w0);
    }
}

// ---------------- agg layer 1: 16 nodes/block, bf16-packed output ----------------
__global__ __launch_bounds__(256) void agg_kernel(const uint4* __restrict__ m4,
                                                  const int* __restrict__ rowstart,
                                                  const int* __restrict__ csr,
                                                  const float* __restrict__ dinv,
                                                  const float* __restrict__ bias,
                                                  uint4* __restrict__ out, int n) {
    int t = threadIdx.x & 15;
    int node = blockIdx.x * 16 + (threadIdx.x >> 4);
    if (node >= n) return;
    float dd = dinv[node];
    float acc[8];
    {   // self term (dinv[dst] factored out of the edge sum)
        uint4 u = m4[(size_t)node * 16 + t];
        acc[0] = dd * bf_lo(u.x); acc[1] = dd * bf_hi(u.x);
        acc[2] = dd * bf_lo(u.y); acc[3] = dd * bf_hi(u.y);
        acc[4] = dd * bf_lo(u.z); acc[5] = dd * bf_hi(u.z);
        acc[6] = dd * bf_lo(u.w); acc[7] = dd * bf_hi(u.w);
    }
    qgather(m4, csr, dinv, rowstart[node], rowstart[node + 1], t, acc);
    float4 b0 = *(const float4*)&bias[t * 8];
    float4 b1 = *(const float4*)&bias[t * 8 + 4];
    uint4 o;
    o.x = bf_pack(fmaxf(fmaf(dd, acc[0], b0.x), 0.f), fmaxf(fmaf(dd, acc[1], b0.y), 0.f));
    o.y = bf_pack(fmaxf(fmaf(dd, acc[2], b0.z), 0.f), fmaxf(fmaf(dd, acc[3], b0.w), 0.f));
    o.z = bf_pack(fmaxf(fmaf(dd, acc[4], b1.x), 0.f), fmaxf(fmaf(dd, acc[5], b1.y), 0.f));
    o.w = bf_pack(fmaxf(fmaf(dd, acc[6], b1.z), 0.f), fmaxf(fmaf(dd, acc[7], b1.w), 0.f));
    out[(size_t)node * 16 + t] = o;
}

// ---------------- agg layer 2 fused with global max pool ----------------
__global__ __launch_bounds__(256) void agg_pool_kernel(const uint4* __restrict__ m4,
                                                       const int* __restrict__ rowstart,
                                                       const int* __restrict__ csr,
                                                       const float* __restrict__ dinv,
                                                       const float* __restrict__ bias,
                                                       const int* __restrict__ batch,
                                                       unsigned int* __restrict__ g, int n) {
    __shared__ float smx[16][HDIM];
    __shared__ int sgid[16];
    int t = threadIdx.x & 15;
    int nl = threadIdx.x >> 4;              // node-in-block 0..15
    int node = blockIdx.x * 16 + nl;
    bool valid = node < n;
    if (valid) {
        float dd = dinv[node];
        float acc[8];
        uint4 u = m4[(size_t)node * 16 + t];
        acc[0] = dd * bf_lo(u.x); acc[1] = dd * bf_hi(u.x);
        acc[2] = dd * bf_lo(u.y); acc[3] = dd * bf_hi(u.y);
        acc[4] = dd * bf_lo(u.z); acc[5] = dd * bf_hi(u.z);
        acc[6] = dd * bf_lo(u.w); acc[7] = dd * bf_hi(u.w);
        qgather(m4, csr, dinv, rowstart[node], rowstart[node + 1], t, acc);
        float4 b0 = *(const float4*)&bias[t * 8];
        float4 b1 = *(const float4*)&bias[t * 8 + 4];
        float4 r0, r1;
        r0.x = fmaxf(fmaf(dd, acc[0], b0.x), 0.f);
        r0.y = fmaxf(fmaf(dd, acc[1], b0.y), 0.f);
        r0.z = fmaxf(fmaf(dd, acc[2], b0.z), 0.f);
        r0.w = fmaxf(fmaf(dd, acc[3], b0.w), 0.f);
        r1.x = fmaxf(fmaf(dd, acc[4], b1.x), 0.f);
        r1.y = fmaxf(fmaf(dd, acc[5], b1.y), 0.f);
        r1.z = fmaxf(fmaf(dd, acc[6], b1.z), 0.f);
        r1.w = fmaxf(fmaf(dd, acc[7], b1.w), 0.f);
        *(float4*)&smx[nl][t * 8] = r0;
        *(float4*)&smx[nl][t * 8 + 4] = r1;
    }
    if (t == 0) sgid[nl] = valid ? batch[node] : -1;
    __syncthreads();
    if (threadIdx.x < HDIM) {
        int c = threadIdx.x;
        int curg = -1;
        float run = 0.f;
#pragma unroll
        for (int r = 0; r < 16; ++r) {
            int gg = sgid[r];
            if (gg < 0) continue;
            if (gg != curg) {
                if (curg >= 0) atomicMax(&g[curg * HDIM + c], __float_as_uint(run));
                curg = gg;
                run = smx[r][c];
            } else {
                run = fmaxf(run, smx[r][c]);
            }
        }
        if (curg >= 0) atomicMax(&g[curg * HDIM + c], __float_as_uint(run));
    }
}

// ---------------- MLP head + log_softmax ----------------
__global__ __launch_bounds__(128) void mlp_kernel(const unsigned int* __restrict__ gbits,
                                                  const float* __restrict__ W3,
                                                  const float* __restrict__ b3,
                                                  const float* __restrict__ W4,
                                                  const float* __restrict__ b4,
                                                  float* __restrict__ out) {
    __shared__ float gs[HDIM];
    __shared__ float r0[HDIM];
    __shared__ float r1[HDIM];
    int j = threadIdx.x;
    int b = blockIdx.x;
    gs[j] = __uint_as_float(gbits[b * HDIM + j]);
    __syncthreads();
    float acc = b3[j];
#pragma unroll 8
    for (int k = 0; k < HDIM; ++k) acc = fmaf(gs[k], W3[k * HDIM + j], acc);
    float z = fmaxf(acc, 0.f);
    r0[j] = z * W4[j * 2 + 0];
    r1[j] = z * W4[j * 2 + 1];
    __syncthreads();
    for (int off = 64; off > 0; off >>= 1) {
        if (j < off) {
            r0[j] += r0[j + off];
            r1[j] += r1[j + off];
        }
        __syncthreads();
    }
    if (j == 0) {
        float l0 = r0[0] + b4[0];
        float l1 = r1[0] + b4[1];
        float mx = fmaxf(l0, l1);
        float lse = mx + logf(expf(l0 - mx) + expf(l1 - mx));
        out[b * 2 + 0] = l0 - lse;
        out[b * 2 + 1] = l1 - lse;
    }
}

extern "C" void kernel_launch(void* const* d_in, const int* in_sizes, int n_in,
                              void* d_out, int out_size, void* d_ws, size_t ws_size,
                              hipStream_t stream) {
    const float* x  = (const float*)d_in[0];
    const float* W1 = (const float*)d_in[1];
    const float* b1 = (const float*)d_in[2];
    const float* W2 = (const float*)d_in[3];
    const float* b2 = (const float*)d_in[4];
    const float* W3 = (const float*)d_in[5];
    const float* b3 = (const float*)d_in[6];
    const float* W4 = (const float*)d_in[7];
    const float* b4 = (const float*)d_in[8];
    const int* ei    = (const int*)d_in[9];
    const int* batch = (const int*)d_in[10];

    const int N = in_sizes[0] / HDIM;   // 50000
    const int E = in_sizes[9] / 2;      // 640000
    const int G = out_size / 2;         // 64
    const int* src = ei;
    const int* dst = ei + E;

    const int nbuck = (N + 255) >> 8;        // 196 (must be <= 256)
    const int nscan = nbuck * NBLK;          // 50176
    const int chunk = (E + NBLK - 1) / NBLK; // 2500

    // ---- workspace layout (16B-aligned blocks) ----
    const int Nr = ((N + 63) / 64) * 64;
    char* wsb = (char*)d_ws;
    size_t o = 0;
    unsigned int* g = (unsigned int*)(wsb + o); o += (size_t)G * HDIM * 4;
    size_t zero_bytes = o;                 // only g needs zeroing
    int* hist = (int*)(wsb + o);           o += (size_t)nscan * 4;
    int* hscan = (int*)(wsb + o);          o += (size_t)nscan * 4;
    int* sums = (int*)(wsb + o);           o += 256 * 4;
    int* rowstart = (int*)(wsb + o);       o += (size_t)(Nr + 64) * 4;
    float* dinv = (float*)(wsb + o);       o += (size_t)Nr * 4;
    int2* sorted = (int2*)(wsb + o);       o += (size_t)E * 8;
    int* csr = (int*)(wsb + o);            o += (size_t)E * 4;
    unsigned short* wf1h = (unsigned short*)(wsb + o); o += (size_t)HDIM * HDIM * 2;
    unsigned short* wf1l = (unsigned short*)(wsb + o); o += (size_t)HDIM * HDIM * 2;
    unsigned short* wf2h = (unsigned short*)(wsb + o); o += (size_t)HDIM * HDIM * 2;
    unsigned short* wf2l = (unsigned short*)(wsb + o); o += (size_t)HDIM * HDIM * 2;
    unsigned short* m = (unsigned short*)(wsb + o);    o += (size_t)Nr * HDIM * 2;
    unsigned short* h = (unsigned short*)(wsb + o);    o += (size_t)Nr * HDIM * 2;
    (void)ws_size; (void)n_in;

    (void)hipMemsetAsync(d_ws, 0, zero_bytes, stream);

    int sblocks = (nscan + SCAN_B - 1) / SCAN_B;   // 196 (<= 256 required)
    int gemm_blocks = (N + GBM - 1) / GBM;         // 782
    int agg_blocks = (N + 15) / 16;

    // K1: hist || wfrag  (independent)
    mega1_kernel<<<NBLK + 128, 256, 0, stream>>>(dst, hist, E, chunk, nbuck,
                                                 W1, W2, wf1h, wf1l, wf2h, wf2l);
    // K2: scan of hist matrix (bucket-major) -> hscan exclusive
    scan1_kernel<<<sblocks, SCAN_B, 0, stream>>>(hist, hscan, sums, nscan);
    scan2_kernel<<<1, SCAN_B, 0, stream>>>(sums, sblocks);
    scan3_kernel<<<sblocks, SCAN_B, 0, stream>>>(hist, hscan, sums, nscan);
    // K3: scatter (bucket sort) || gemm layer 1
    mega3_kernel<<<NBLK + gemm_blocks, 256, 0, stream>>>(src, dst, hscan, sorted,
                                                         E, chunk, nbuck,
                                                         x, wf1h, wf1l, m, N);
    // K4: per-bucket CSR build (rowstart, dinv, csr)
    csr_kernel<<<nbuck, 256, 0, stream>>>(sorted, hscan, rowstart, dinv, csr, N, E, nbuck);
    // layer 1 aggregate
    agg_kernel<<<agg_blocks, 256, 0, stream>>>((const uint4*)m, rowstart, csr,
                                               dinv, b1, (uint4*)h, N);
    // layer 2: m = bf16(h@W2); g = segmax(relu(dinv.*agg(m)+b2))  [pool fused]
    gemm_bf16_kernel<<<gemm_blocks, 256, 0, stream>>>(h, wf2h, wf2l, m, N);
    agg_pool_kernel<<<agg_blocks, 256, 0, stream>>>((const uint4*)m, rowstart, csr,
                                                    dinv, b2, batch, g, N);
    // MLP head + log_softmax
    mlp_kernel<<<G, 128, 0, stream>>>(g, W3, b3, W4, b4, (float*)d_out);
}

// Round 9
// 201.712 us; speedup vs baseline: 2.0361x; 1.0200x over previous
//
#include <hip/hip_runtime.h>
#include <hip/hip_bf16.h>
#include <math.h>

// ---------------- constants ----------------
#define HDIM 128
#define SCAN_B 256
#define NBLK 256          // edge blocks for hist/scatter passes

typedef short bfrag __attribute__((ext_vector_type(8)));   // 8 bf16 (4 VGPRs)
typedef float f32x4 __attribute__((ext_vector_type(4)));   // 4 fp32 acc

__device__ inline unsigned short f2bf_rne(float x) {
    unsigned u = __float_as_uint(x);
    u = (u + 0x7fffu + ((u >> 16) & 1u)) >> 16;
    return (unsigned short)u;
}
__device__ inline float bf_lo(unsigned u) { return __uint_as_float(u << 16); }
__device__ inline float bf_hi(unsigned u) { return __uint_as_float(u & 0xffff0000u); }
__device__ inline unsigned bf_pack(float lo, float hi) {
    return ((unsigned)f2bf_rne(hi) << 16) | (unsigned)f2bf_rne(lo);
}

// ---------------- device bodies ----------------

// Pass A: per-block LDS histogram over coarse buckets (dst>>8); no global atomics.
__device__ inline void hist_body(int b, const int* __restrict__ dst,
                                 int* __restrict__ hist, int E, int chunk, int nbuck) {
    __shared__ int hl[256];
    int t = threadIdx.x;
    hl[t] = 0;
    __syncthreads();
    int start = b * chunk, end = min(E, start + chunk);
    for (int e = start + t; e < end; e += 256) atomicAdd(&hl[dst[e] >> 8], 1);
    __syncthreads();
    if (t < nbuck) hist[t * NBLK + b] = hl[t];
}

// W -> fragment-ordered bf16 hi/lo, column-permuted: physical slot (nt, lm)
// carries logical column n_l = lm*8 + nt (so epilogue stores are 16B packed).
__device__ inline void wfrag_body(int b, const float* __restrict__ W1,
                                  const float* __restrict__ W2,
                                  unsigned short* __restrict__ w1h,
                                  unsigned short* __restrict__ w1l,
                                  unsigned short* __restrict__ w2h,
                                  unsigned short* __restrict__ w2l) {
    const float* W = (b < 64) ? W1 : W2;
    unsigned short* whi = (b < 64) ? w1h : w2h;
    unsigned short* wlo = (b < 64) ? w1l : w2l;
    int idx = (b & 63) * 256 + threadIdx.x;     // 0..16383
    int k = idx >> 7;
    int n = idx & 127;
    int kt = k >> 5, q = (k >> 3) & 3, j = k & 7;
    int lm = n >> 3, nt = n & 7;
    int lane = q * 16 + lm;
    int o = ((kt * 8 + nt) * 64 + lane) * 8 + j;
    float x = W[idx];
    unsigned short hb = f2bf_rne(x);
    float hf = __uint_as_float(((unsigned)hb) << 16);
    unsigned short lb = f2bf_rne(x - hf);
    whi[o] = hb;
    wlo[o] = lb;
}

// Pass C: scatter edges into bucket-sorted order via LDS cursors (no global atomics).
__device__ inline void scatter_body(int b, const int* __restrict__ srcv,
                                    const int* __restrict__ dstv,
                                    const int* __restrict__ hscan,
                                    int2* __restrict__ sorted,
                                    int E, int chunk, int nbuck) {
    __shared__ int cur[256];
    int t = threadIdx.x;
    if (t < nbuck) cur[t] = hscan[t * NBLK + b];
    __syncthreads();
    int start = b * chunk, end = min(E, start + chunk);
    for (int e = start + t; e < end; e += 256) {
        int d = dstv[e];
        int pos = atomicAdd(&cur[d >> 8], 1);
        sorted[pos] = make_int2(srcv[e], d);
    }
}

// MFMA GEMM (fp32 A), 64-row tiles, split 3-MFMA: C ~= Ah*Wh + Al*Wh + Ah*Wl
#define GBM 64
__device__ inline void gemm_f32_body(int b, const float* __restrict__ A,
                                     const unsigned short* __restrict__ whi,
                                     const unsigned short* __restrict__ wlo,
                                     unsigned short* __restrict__ C, int Nrows) {
    int tid = threadIdx.x;
    int w = tid >> 6, L = tid & 63;
    int lm = L & 15, lq = L >> 4;
    int row0 = b * GBM + w * 16;

    f32x4 acc[8];
#pragma unroll
    for (int nt = 0; nt < 8; ++nt) acc[nt] = (f32x4)(0.f);

#pragma unroll
    for (int kt = 0; kt < 4; ++kt) {
        int gr = row0 + lm;
        float4 v0 = make_float4(0.f, 0.f, 0.f, 0.f);
        float4 v1 = v0;
        if (gr < Nrows) {
            const float* p = &A[(size_t)gr * HDIM + kt * 32 + lq * 8];
            v0 = *(const float4*)p;
            v1 = *(const float4*)(p + 4);
        }
        float xv[8] = {v0.x, v0.y, v0.z, v0.w, v1.x, v1.y, v1.z, v1.w};
        bfrag ah, al;
#pragma unroll
        for (int j = 0; j < 8; ++j) {
            float x = xv[j];
            unsigned short hb = f2bf_rne(x);
            float hf = __uint_as_float(((unsigned)hb) << 16);
            unsigned short lb = f2bf_rne(x - hf);
            ah[j] = (short)hb;
            al[j] = (short)lb;
        }
#pragma unroll
        for (int nt = 0; nt < 8; ++nt) {
            int o = ((kt * 8 + nt) * 64 + L) * 8;
            bfrag wh = *(const bfrag*)&whi[o];
            bfrag wl = *(const bfrag*)&wlo[o];
            acc[nt] = __builtin_amdgcn_mfma_f32_16x16x32_bf16(ah, wh, acc[nt], 0, 0, 0);
            acc[nt] = __builtin_amdgcn_mfma_f32_16x16x32_bf16(al, wh, acc[nt], 0, 0, 0);
            acc[nt] = __builtin_amdgcn_mfma_f32_16x16x32_bf16(ah, wl, acc[nt], 0, 0, 0);
        }
    }

#pragma unroll
    for (int i = 0; i < 4; ++i) {
        int gr = row0 + lq * 4 + i;
        if (gr < Nrows) {
            bfrag e;
#pragma unroll
            for (int nt = 0; nt < 8; ++nt) e[nt] = (short)f2bf_rne(acc[nt][i]);
            *(bfrag*)&C[(size_t)gr * HDIM + lm * 8] = e;
        }
    }
}

// ---------------- megakernel 1: hist || wfrag ----------------
__global__ __launch_bounds__(256) void mega1_kernel(const int* __restrict__ dst,
                                                    int* __restrict__ hist, int E,
                                                    int chunk, int nbuck,
                                                    const float* __restrict__ W1,
                                                    const float* __restrict__ W2,
                                                    unsigned short* __restrict__ w1h,
                                                    unsigned short* __restrict__ w1l,
                                                    unsigned short* __restrict__ w2h,
                                                    unsigned short* __restrict__ w2l) {
    int b = blockIdx.x;
    if (b < NBLK) hist_body(b, dst, hist, E, chunk, nbuck);
    else wfrag_body(b - NBLK, W1, W2, w1h, w1l, w2h, w2l);
}

// ---------------- megakernel 3: scatter || gemm_f32(layer1) ----------------
__global__ __launch_bounds__(256) void mega3_kernel(const int* __restrict__ srcv,
                                                    const int* __restrict__ dstv,
                                                    const int* __restrict__ hscan,
                                                    int2* __restrict__ sorted,
                                                    int E, int chunk, int nbuck,
                                                    const float* __restrict__ A,
                                                    const unsigned short* __restrict__ whi,
                                                    const unsigned short* __restrict__ wlo,
                                                    unsigned short* __restrict__ C, int Nrows) {
    int b = blockIdx.x;
    if (b < NBLK) scatter_body(b, srcv, dstv, hscan, sorted, E, chunk, nbuck);
    else gemm_f32_body(b - NBLK, A, whi, wlo, C, Nrows);
}

// ---------------- generic 3-phase scan (n <= 256*256) ----------------
__global__ __launch_bounds__(SCAN_B) void scan1_kernel(const int* __restrict__ in,
                                                       int* __restrict__ out,
                                                       int* __restrict__ sums, int n) {
    __shared__ int s[SCAN_B];
    int t = threadIdx.x;
    int idx = blockIdx.x * SCAN_B + t;
    int v = (idx < n) ? in[idx] : 0;
    s[t] = v;
    __syncthreads();
    for (int off = 1; off < SCAN_B; off <<= 1) {
        int x = (t >= off) ? s[t - off] : 0;
        __syncthreads();
        s[t] += x;
        __syncthreads();
    }
    if (idx < n) out[idx] = s[t];
    if (t == SCAN_B - 1) sums[blockIdx.x] = s[t];
}

__global__ __launch_bounds__(SCAN_B) void scan2_kernel(int* __restrict__ sums, int nb) {
    __shared__ int s[SCAN_B];
    int t = threadIdx.x;
    int v = (t < nb) ? sums[t] : 0;
    s[t] = v;
    __syncthreads();
    for (int off = 1; off < SCAN_B; off <<= 1) {
        int x = (t >= off) ? s[t - off] : 0;
        __syncthreads();
        s[t] += x;
        __syncthreads();
    }
    if (t < nb) sums[t] = s[t] - v;
}

// out[idx] = exclusive scan (needs original in[])
__global__ __launch_bounds__(SCAN_B) void scan3_kernel(const int* __restrict__ in,
                                                       int* __restrict__ out,
                                                       const int* __restrict__ sums, int n) {
    int idx = blockIdx.x * SCAN_B + threadIdx.x;
    if (idx < n) out[idx] = out[idx] - in[idx] + sums[blockIdx.x];
}

// ---------------- Pass D: per-bucket CSR build (LDS atomics only) ----------------
__global__ __launch_bounds__(256) void csr_kernel(const int2* __restrict__ sorted,
                                                  const int* __restrict__ hscan,
                                                  int* __restrict__ rowstart,
                                                  float* __restrict__ dinv,
                                                  int* __restrict__ csr,
                                                  int N, int E, int nbuck) {
    __shared__ int cnt[256];
    __shared__ int s[256];
    __shared__ int cur[256];
    int b = blockIdx.x;
    int t = threadIdx.x;
    int start = hscan[b * NBLK];
    int end = (b + 1 < nbuck) ? hscan[(b + 1) * NBLK] : E;
    cnt[t] = 0;
    __syncthreads();
    for (int e = start + t; e < end; e += 256)
        atomicAdd(&cnt[sorted[e].y & 255], 1);
    __syncthreads();
    int v = cnt[t];
    s[t] = v;
    __syncthreads();
    for (int off = 1; off < 256; off <<= 1) {
        int x = (t >= off) ? s[t - off] : 0;
        __syncthreads();
        s[t] += x;
        __syncthreads();
    }
    int excl = s[t] - v;
    int node = b * 256 + t;
    if (node < N) {
        rowstart[node] = start + excl;
        dinv[node] = rsqrtf((float)(v + 1));   // +1 self-loop
    }
    if (b == nbuck - 1 && t == 0) rowstart[N] = E;
    cur[t] = start + excl;
    __syncthreads();
    for (int e = start + t; e < end; e += 256) {
        int2 ed = sorted[e];
        int pos = atomicAdd(&cur[ed.y & 255], 1);
        csr[pos] = ed.x;
    }
}

// ---------------- quarter-wave gather, 8-deep software pipeline ----------------
#define QACC(UV, WT)                                   \
    acc[0] = fmaf(WT, bf_lo((UV).x), acc[0]);          \
    acc[1] = fmaf(WT, bf_hi((UV).x), acc[1]);          \
    acc[2] = fmaf(WT, bf_lo((UV).y), acc[2]);          \
    acc[3] = fmaf(WT, bf_hi((UV).y), acc[3]);          \
    acc[4] = fmaf(WT, bf_lo((UV).z), acc[4]);          \
    acc[5] = fmaf(WT, bf_hi((UV).z), acc[5]);          \
    acc[6] = fmaf(WT, bf_lo((UV).w), acc[6]);          \
    acc[7] = fmaf(WT, bf_hi((UV).w), acc[7]);

__device__ inline void qgather(const uint4* __restrict__ m4,
                               const int* __restrict__ csr,
                               const float* __restrict__ dinv,
                               int p, int pend, int t, float* acc) {
    for (; p + 8 <= pend; p += 8) {
        int s0 = csr[p], s1 = csr[p + 1], s2 = csr[p + 2], s3 = csr[p + 3];
        int s4 = csr[p + 4], s5 = csr[p + 5], s6 = csr[p + 6], s7 = csr[p + 7];
        float w0 = dinv[s0], w1 = dinv[s1], w2 = dinv[s2], w3 = dinv[s3];
        float w4 = dinv[s4], w5 = dinv[s5], w6 = dinv[s6], w7 = dinv[s7];
        uint4 u0 = m4[(size_t)s0 * 16 + t];
        uint4 u1 = m4[(size_t)s1 * 16 + t];
        uint4 u2 = m4[(size_t)s2 * 16 + t];
        uint4 u3 = m4[(size_t)s3 * 16 + t];
        uint4 u4 = m4[(size_t)s4 * 16 + t];
        uint4 u5 = m4[(size_t)s5 * 16 + t];
        uint4 u6 = m4[(size_t)s6 * 16 + t];
        uint4 u7 = m4[(size_t)s7 * 16 + t];
        QACC(u0, w0); QACC(u1, w1); QACC(u2, w2); QACC(u3, w3);
        QACC(u4, w4); QACC(u5, w5); QACC(u6, w6); QACC(u7, w7);
    }
    if (p + 4 <= pend) {
        int s0 = csr[p], s1 = csr[p + 1], s2 = csr[p + 2], s3 = csr[p + 3];
        float w0 = dinv[s0], w1 = dinv[s1], w2 = dinv[s2], w3 = dinv[s3];
        uint4 u0 = m4[(size_t)s0 * 16 + t];
        uint4 u1 = m4[(size_t)s1 * 16 + t];
        uint4 u2 = m4[(size_t)s2 * 16 + t];
        uint4 u3 = m4[(size_t)s3 * 16 + t];
        QACC(u0, w0); QACC(u1, w1); QACC(u2, w2); QACC(u3, w3);
        p += 4;
    }
    if (p + 2 <= pend) {
        int s0 = csr[p], s1 = csr[p + 1];
        float w0 = dinv[s0], w1 = dinv[s1];
        uint4 u0 = m4[(size_t)s0 * 16 + t];
        uint4 u1 = m4[(size_t)s1 * 16 + t];
        QACC(u0, w0); QACC(u1, w1);
        p += 2;
    }
    if (p < pend) {
        int s0 = csr[p];
        float w0 = dinv[s0];
        uint4 u0 = m4[(size_t)s0 * 16 + t];
        QACC(u0, w0);
    }
}

// ---------------- fused agg(layer1) + gemm(layer2): m2 = bf16(relu(agg)+b1)@W2 ----------------
// Per block: 16 nodes. Agg phase (quarter-wave), round to bf16 in LDS (identical
// rounding to the old h store), then in-block 16x128 @ 128x128 MFMA, repack via
// padded fp32 LDS tile, write m2 rows packed bf16.
__global__ __launch_bounds__(256) void agg_gemm_kernel(
        const uint4* __restrict__ m4,
        const int* __restrict__ rowstart,
        const int* __restrict__ csr,
        const float* __restrict__ dinv,
        const float* __restrict__ bias,
        const unsigned short* __restrict__ whi,   // W2 frags
        const unsigned short* __restrict__ wlo,
        uint4* __restrict__ out_m, int n) {
    __shared__ unsigned short hbuf[16][HDIM + 8];   // bf16 h tile (+16B pad)
    __shared__ float cbuf[16][HDIM + 4];            // fp32 C tile (+16B pad)
    int t = threadIdx.x & 15;
    int nl = threadIdx.x >> 4;
    int node = blockIdx.x * 16 + nl;

    // ---- agg phase ----
    unsigned short hv[8] = {0, 0, 0, 0, 0, 0, 0, 0};
    if (node < n) {
        float dd = dinv[node];
        float acc[8];
        uint4 u = m4[(size_t)node * 16 + t];
        acc[0] = dd * bf_lo(u.x); acc[1] = dd * bf_hi(u.x);
        acc[2] = dd * bf_lo(u.y); acc[3] = dd * bf_hi(u.y);
        acc[4] = dd * bf_lo(u.z); acc[5] = dd * bf_hi(u.z);
        acc[6] = dd * bf_lo(u.w); acc[7] = dd * bf_hi(u.w);
        qgather(m4, csr, dinv, rowstart[node], rowstart[node + 1], t, acc);
        float4 b0 = *(const float4*)&bias[t * 8];
        float4 b1 = *(const float4*)&bias[t * 8 + 4];
        float bb[8] = {b0.x, b0.y, b0.z, b0.w, b1.x, b1.y, b1.z, b1.w};
#pragma unroll
        for (int j = 0; j < 8; ++j)
            hv[j] = f2bf_rne(fmaxf(fmaf(dd, acc[j], bb[j]), 0.f));
    }
    *(uint4*)&hbuf[nl][t * 8] = *(uint4*)hv;
    __syncthreads();

    // ---- gemm phase: each wave does 2 column tiles, all 4 kt ----
    int w = threadIdx.x >> 6, L = threadIdx.x & 63;
    int lm = L & 15, lq = L >> 4;
    f32x4 acc2[2];
    acc2[0] = (f32x4)(0.f);
    acc2[1] = (f32x4)(0.f);
#pragma unroll
    for (int kt = 0; kt < 4; ++kt) {
        bfrag a = *(const bfrag*)&hbuf[lm][kt * 32 + lq * 8];
#pragma unroll
        for (int q2 = 0; q2 < 2; ++q2) {
            int nt = w * 2 + q2;
            int o = ((kt * 8 + nt) * 64 + L) * 8;
            bfrag wh = *(const bfrag*)&whi[o];
            bfrag wl = *(const bfrag*)&wlo[o];
            acc2[q2] = __builtin_amdgcn_mfma_f32_16x16x32_bf16(a, wh, acc2[q2], 0, 0, 0);
            acc2[q2] = __builtin_amdgcn_mfma_f32_16x16x32_bf16(a, wl, acc2[q2], 0, 0, 0);
        }
    }
    // C/D layout: col(in tile)=lane&15, row=(lane>>4)*4+i; logical col = lm*8+nt
#pragma unroll
    for (int q2 = 0; q2 < 2; ++q2) {
        int nt = w * 2 + q2;
#pragma unroll
        for (int i = 0; i < 4; ++i) cbuf[lq * 4 + i][lm * 8 + nt] = acc2[q2][i];
    }
    __syncthreads();

    // ---- repack + round + store ----
    if (node < n) {
        float4 r0 = *(const float4*)&cbuf[nl][t * 8];
        float4 r1 = *(const float4*)&cbuf[nl][t * 8 + 4];
        unsigned short ev[8];
        ev[0] = f2bf_rne(r0.x); ev[1] = f2bf_rne(r0.y);
        ev[2] = f2bf_rne(r0.z); ev[3] = f2bf_rne(r0.w);
        ev[4] = f2bf_rne(r1.x); ev[5] = f2bf_rne(r1.y);
        ev[6] = f2bf_rne(r1.z); ev[7] = f2bf_rne(r1.w);
        out_m[(size_t)node * 16 + t] = *(uint4*)ev;
    }
}

// ---------------- agg layer 2 fused with global max pool ----------------
__global__ __launch_bounds__(256) void agg_pool_kernel(const uint4* __restrict__ m4,
                                                       const int* __restrict__ rowstart,
                                                       const int* __restrict__ csr,
                                                       const float* __restrict__ dinv,
                                                       const float* __restrict__ bias,
                                                       const int* __restrict__ batch,
                                                       unsigned int* __restrict__ g, int n) {
    __shared__ float smx[16][HDIM];
    __shared__ int sgid[16];
    int t = threadIdx.x & 15;
    int nl = threadIdx.x >> 4;              // node-in-block 0..15
    int node = blockIdx.x * 16 + nl;
    bool valid = node < n;
    if (valid) {
        float dd = dinv[node];
        float acc[8];
        uint4 u = m4[(size_t)node * 16 + t];
        acc[0] = dd * bf_lo(u.x); acc[1] = dd * bf_hi(u.x);
        acc[2] = dd * bf_lo(u.y); acc[3] = dd * bf_hi(u.y);
        acc[4] = dd * bf_lo(u.z); acc[5] = dd * bf_hi(u.z);
        acc[6] = dd * bf_lo(u.w); acc[7] = dd * bf_hi(u.w);
        qgather(m4, csr, dinv, rowstart[node], rowstart[node + 1], t, acc);
        float4 b0 = *(const float4*)&bias[t * 8];
        float4 b1 = *(const float4*)&bias[t * 8 + 4];
        float4 r0, r1;
        r0.x = fmaxf(fmaf(dd, acc[0], b0.x), 0.f);
        r0.y = fmaxf(fmaf(dd, acc[1], b0.y), 0.f);
        r0.z = fmaxf(fmaf(dd, acc[2], b0.z), 0.f);
        r0.w = fmaxf(fmaf(dd, acc[3], b0.w), 0.f);
        r1.x = fmaxf(fmaf(dd, acc[4], b1.x), 0.f);
        r1.y = fmaxf(fmaf(dd, acc[5], b1.y), 0.f);
        r1.z = fmaxf(fmaf(dd, acc[6], b1.z), 0.f);
        r1.w = fmaxf(fmaf(dd, acc[7], b1.w), 0.f);
        *(float4*)&smx[nl][t * 8] = r0;
        *(float4*)&smx[nl][t * 8 + 4] = r1;
    }
    if (t == 0) sgid[nl] = valid ? batch[node] : -1;
    __syncthreads();
    if (threadIdx.x < HDIM) {
        int c = threadIdx.x;
        int curg = -1;
        float run = 0.f;
#pragma unroll
        for (int r = 0; r < 16; ++r) {
            int gg = sgid[r];
            if (gg < 0) continue;
            if (gg != curg) {
                if (curg >= 0) atomicMax(&g[curg * HDIM + c], __float_as_uint(run));
                curg = gg;
                run = smx[r][c];
            } else {
                run = fmaxf(run, smx[r][c]);
            }
        }
        if (curg >= 0) atomicMax(&g[curg * HDIM + c], __float_as_uint(run));
    }
}

// ---------------- MLP head + log_softmax ----------------
__global__ __launch_bounds__(128) void mlp_kernel(const unsigned int* __restrict__ gbits,
                                                  const float* __restrict__ W3,
                                                  const float* __restrict__ b3,
                                                  const float* __restrict__ W4,
                                                  const float* __restrict__ b4,
                                                  float* __restrict__ out) {
    __shared__ float gs[HDIM];
    __shared__ float r0[HDIM];
    __shared__ float r1[HDIM];
    int j = threadIdx.x;
    int b = blockIdx.x;
    gs[j] = __uint_as_float(gbits[b * HDIM + j]);
    __syncthreads();
    float acc = b3[j];
#pragma unroll 8
    for (int k = 0; k < HDIM; ++k) acc = fmaf(gs[k], W3[k * HDIM + j], acc);
    float z = fmaxf(acc, 0.f);
    r0[j] = z * W4[j * 2 + 0];
    r1[j] = z * W4[j * 2 + 1];
    __syncthreads();
    for (int off = 64; off > 0; off >>= 1) {
        if (j < off) {
            r0[j] += r0[j + off];
            r1[j] += r1[j + off];
        }
        __syncthreads();
    }
    if (j == 0) {
        float l0 = r0[0] + b4[0];
        float l1 = r1[0] + b4[1];
        float mx = fmaxf(l0, l1);
        float lse = mx + logf(expf(l0 - mx) + expf(l1 - mx));
        out[b * 2 + 0] = l0 - lse;
        out[b * 2 + 1] = l1 - lse;
    }
}

extern "C" void kernel_launch(void* const* d_in, const int* in_sizes, int n_in,
                              void* d_out, int out_size, void* d_ws, size_t ws_size,
                              hipStream_t stream) {
    const float* x  = (const float*)d_in[0];
    const float* W1 = (const float*)d_in[1];
    const float* b1 = (const float*)d_in[2];
    const float* W2 = (const float*)d_in[3];
    const float* b2 = (const float*)d_in[4];
    const float* W3 = (const float*)d_in[5];
    const float* b3 = (const float*)d_in[6];
    const float* W4 = (const float*)d_in[7];
    const float* b4 = (const float*)d_in[8];
    const int* ei    = (const int*)d_in[9];
    const int* batch = (const int*)d_in[10];

    const int N = in_sizes[0] / HDIM;   // 50000
    const int E = in_sizes[9] / 2;      // 640000
    const int G = out_size / 2;         // 64
    const int* src = ei;
    const int* dst = ei + E;

    const int nbuck = (N + 255) >> 8;        // 196 (must be <= 256)
    const int nscan = nbuck * NBLK;          // 50176
    const int chunk = (E + NBLK - 1) / NBLK; // 2500

    // ---- workspace layout (16B-aligned blocks) ----
    const int Nr = ((N + 63) / 64) * 64;
    char* wsb = (char*)d_ws;
    size_t o = 0;
    unsigned int* g = (unsigned int*)(wsb + o); o += (size_t)G * HDIM * 4;
    size_t zero_bytes = o;                 // only g needs zeroing
    int* hist = (int*)(wsb + o);           o += (size_t)nscan * 4;
    int* hscan = (int*)(wsb + o);          o += (size_t)nscan * 4;
    int* sums = (int*)(wsb + o);           o += 256 * 4;
    int* rowstart = (int*)(wsb + o);       o += (size_t)(Nr + 64) * 4;
    float* dinv = (float*)(wsb + o);       o += (size_t)Nr * 4;
    int2* sorted = (int2*)(wsb + o);       o += (size_t)E * 8;
    int* csr = (int*)(wsb + o);            o += (size_t)E * 4;
    unsigned short* wf1h = (unsigned short*)(wsb + o); o += (size_t)HDIM * HDIM * 2;
    unsigned short* wf1l = (unsigned short*)(wsb + o); o += (size_t)HDIM * HDIM * 2;
    unsigned short* wf2h = (unsigned short*)(wsb + o); o += (size_t)HDIM * HDIM * 2;
    unsigned short* wf2l = (unsigned short*)(wsb + o); o += (size_t)HDIM * HDIM * 2;
    unsigned short* m = (unsigned short*)(wsb + o);    o += (size_t)Nr * HDIM * 2;
    unsigned short* m2 = (unsigned short*)(wsb + o);   o += (size_t)Nr * HDIM * 2;
    (void)ws_size; (void)n_in;

    (void)hipMemsetAsync(d_ws, 0, zero_bytes, stream);

    int sblocks = (nscan + SCAN_B - 1) / SCAN_B;   // 196 (<= 256 required)
    int gemm_blocks = (N + GBM - 1) / GBM;         // 782
    int agg_blocks = (N + 15) / 16;                // 3125

    // K1: hist || wfrag  (independent)
    mega1_kernel<<<NBLK + 128, 256, 0, stream>>>(dst, hist, E, chunk, nbuck,
                                                 W1, W2, wf1h, wf1l, wf2h, wf2l);
    // K2: scan of hist matrix (bucket-major) -> hscan exclusive
    scan1_kernel<<<sblocks, SCAN_B, 0, stream>>>(hist, hscan, sums, nscan);
    scan2_kernel<<<1, SCAN_B, 0, stream>>>(sums, sblocks);
    scan3_kernel<<<sblocks, SCAN_B, 0, stream>>>(hist, hscan, sums, nscan);
    // K3: scatter (bucket sort) || gemm layer 1
    mega3_kernel<<<NBLK + gemm_blocks, 256, 0, stream>>>(src, dst, hscan, sorted,
                                                         E, chunk, nbuck,
                                                         x, wf1h, wf1l, m, N);
    // K4: per-bucket CSR build (rowstart, dinv, csr)
    csr_kernel<<<nbuck, 256, 0, stream>>>(sorted, hscan, rowstart, dinv, csr, N, E, nbuck);
    // K5: fused agg(layer1) + gemm(layer2) -> m2
    agg_gemm_kernel<<<agg_blocks, 256, 0, stream>>>((const uint4*)m, rowstart, csr,
                                                    dinv, b1, wf2h, wf2l,
                                                    (uint4*)m2, N);
    // K6: agg layer 2 + global max pool
    agg_pool_kernel<<<agg_blocks, 256, 0, stream>>>((const uint4*)m2, rowstart, csr,
                                                    dinv, b2, batch, g, N);
    // K7: MLP head + log_softmax
    mlp_kernel<<<G, 128, 0, stream>>>(g, W3, b3, W4, b4, (float*)d_out);
}